// Round 1
// baseline (6022.446 us; speedup 1.0000x reference)
//
#include <hip/hip_runtime.h>

#define D 128

// ---------------- GEMM: out[r,i] = act( scale_r * sum_j X[r,j] * W[i*ldw+woff+j] ) --------
// W^T staged in LDS with XOR swizzle (by j&31) so both the coalesced global read
// (consecutive j at fixed i) and the LDS write/read are bank-conflict-free.
__global__ __launch_bounds__(256) void gemm_xwt(
    const float* __restrict__ X, const float* __restrict__ W,
    int ldw, int woff, const float* __restrict__ cntscale,
    float* __restrict__ out, int R, int doRelu)
{
    __shared__ float Ws[D * D];   // 64 KB
    const int t = threadIdx.x;
    for (int idx = t; idx < D * D; idx += 256) {
        int i = idx >> 7, j = idx & (D - 1);
        Ws[j * D + (i ^ (j & 31))] = W[i * ldw + woff + j];
    }
    __syncthreads();
    const int lane = t & 63, wave = t >> 6;
    for (int it = 0; it < 4; ++it) {
        int r0 = blockIdx.x * 64 + it * 16 + wave * 4;
        if (r0 >= R) break;
        int r[4];
#pragma unroll
        for (int rr = 0; rr < 4; ++rr) r[rr] = min(r0 + rr, R - 1);
        float acc[4][2] = {};
        const float4* x0 = (const float4*)(X + (size_t)r[0] * D);
        const float4* x1 = (const float4*)(X + (size_t)r[1] * D);
        const float4* x2 = (const float4*)(X + (size_t)r[2] * D);
        const float4* x3 = (const float4*)(X + (size_t)r[3] * D);
        for (int j4 = 0; j4 < D / 4; ++j4) {
            float4 xa = x0[j4], xb = x1[j4], xc = x2[j4], xd = x3[j4];
#pragma unroll
            for (int jj = 0; jj < 4; ++jj) {
                int j = j4 * 4 + jj;
                int sw = j & 31;
                float w0 = Ws[j * D + (lane ^ sw)];
                float w1 = Ws[j * D + ((lane + 64) ^ sw)];
                float va = (jj == 0) ? xa.x : (jj == 1) ? xa.y : (jj == 2) ? xa.z : xa.w;
                float vb = (jj == 0) ? xb.x : (jj == 1) ? xb.y : (jj == 2) ? xb.z : xb.w;
                float vc = (jj == 0) ? xc.x : (jj == 1) ? xc.y : (jj == 2) ? xc.z : xc.w;
                float vd = (jj == 0) ? xd.x : (jj == 1) ? xd.y : (jj == 2) ? xd.z : xd.w;
                acc[0][0] += va * w0; acc[0][1] += va * w1;
                acc[1][0] += vb * w0; acc[1][1] += vb * w1;
                acc[2][0] += vc * w0; acc[2][1] += vc * w1;
                acc[3][0] += vd * w0; acc[3][1] += vd * w1;
            }
        }
#pragma unroll
        for (int rr = 0; rr < 4; ++rr) {
            int rw = r0 + rr;
            if (rw >= R) break;
            float s = cntscale ? (1.0f / fmaxf(cntscale[rw], 1.0f)) : 1.0f;
            float v0 = acc[rr][0] * s, v1 = acc[rr][1] * s;
            if (doRelu) { v0 = fmaxf(v0, 0.0f); v1 = fmaxf(v1, 0.0f); }
            out[(size_t)rw * D + lane] = v0;
            out[(size_t)rw * D + 64 + lane] = v1;
        }
    }
}

// ---------------- counts: cntV[v]++, cntE[e]++, sdvE[e] += invDV[v] ----------------------
__global__ __launch_bounds__(256) void count_kernel(
    const int* __restrict__ inc_v, const int* __restrict__ inc_e,
    const float* __restrict__ invDV,
    float* __restrict__ cntV, float* __restrict__ cntE, float* __restrict__ sdvE, int E)
{
    int k = blockIdx.x * 256 + threadIdx.x;
    if (k >= E) return;
    int v = inc_v[k], e = inc_e[k];
    atomicAdd(cntV + v, 1.0f);
    atomicAdd(cntE + e, 1.0f);
    atomicAdd(sdvE + e, invDV[v]);
}

// ---------------- segment scatter-accumulate: dst[didx[k]] += src[gidx[k]] * gscale[gidx[k]]
__global__ __launch_bounds__(256) void seg_accum(
    const float* __restrict__ src, const int* __restrict__ gidx,
    const int* __restrict__ didx, const float* __restrict__ gscale,
    float* __restrict__ dst, int n)
{
    int gid = blockIdx.x * 256 + threadIdx.x;
    int k = gid >> 5;
    if (k >= n) return;
    int c = (gid & 31) * 4;
    int gs = gidx[k], gd = didx[k];
    float s = gscale ? gscale[gs] : 1.0f;
    float4 v = *(const float4*)(src + (size_t)gs * D + c);
    float* d = dst + (size_t)gd * D + c;
    atomicAdd(d + 0, v.x * s);
    atomicAdd(d + 1, v.y * s);
    atomicAdd(d + 2, v.z * s);
    atomicAdd(d + 3, v.w * s);
}

// ---------------- spmm: dst[row[k]] += val[k] * src[col[k]] (/max(cnt[col],1) if cnt) ----
__global__ __launch_bounds__(256) void spmm_accum(
    const float* __restrict__ src, const int* __restrict__ rows,
    const int* __restrict__ cols, const float* __restrict__ vals,
    const float* __restrict__ cnt_col, float* __restrict__ dst, int nnz)
{
    int gid = blockIdx.x * 256 + threadIdx.x;
    int k = gid >> 5;
    if (k >= nnz) return;
    int c = (gid & 31) * 4;
    int row = rows[k], col = cols[k];
    float s = vals[k];
    if (cnt_col) s *= 1.0f / fmaxf(cnt_col[col], 1.0f);
    float4 v = *(const float4*)(src + (size_t)col * D + c);
    float* d = dst + (size_t)row * D + c;
    atomicAdd(d + 0, v.x * s);
    atomicAdd(d + 1, v.y * s);
    atomicAdd(d + 2, v.z * s);
    atomicAdd(d + 3, v.w * s);
}

// ---------------- A[e] = (acc + (pe1 + b1)*sdv[e]) / max(cntE[e],1)  (in-place on acc) ---
__global__ __launch_bounds__(256) void finalizeA(
    float* __restrict__ acc, const float* __restrict__ pe1,
    const float* __restrict__ b1, const float* __restrict__ sdv,
    const float* __restrict__ cnt, int M)
{
    int gid = blockIdx.x * 256 + threadIdx.x;
    int e = gid >> 5;
    if (e >= M) return;
    int c = (gid & 31) * 4;
    float rs = 1.0f / fmaxf(cnt[e], 1.0f);
    float sd = sdv[e];
    float4 a = *(float4*)(acc + (size_t)e * D + c);
    float4 p = *(const float4*)(pe1 + (size_t)e * D + c);
    float4 b = *(const float4*)(b1 + c);
    a.x = (a.x + (p.x + b.x) * sd) * rs;
    a.y = (a.y + (p.y + b.y) * sd) * rs;
    a.z = (a.z + (p.z + b.z) * sd) * rs;
    a.w = (a.w + (p.w + b.w) * sd) * rs;
    *(float4*)(acc + (size_t)e * D + c) = a;
}

// ---------------- dst += add (elementwise float4) ----------------------------------------
__global__ __launch_bounds__(256) void add_inplace(
    float* __restrict__ dst, const float* __restrict__ add, int total4)
{
    int gid = blockIdx.x * 256 + threadIdx.x;
    if (gid >= total4) return;
    float4 a = *(float4*)(dst + (size_t)gid * 4);
    float4 b = *(const float4*)(add + (size_t)gid * 4);
    a.x += b.x; a.y += b.y; a.z += b.z; a.w += b.w;
    *(float4*)(dst + (size_t)gid * 4) = a;
}

// ---------------- B[e] = acc/max(cnt,1) + (cnt>0 ? pe2 + b2 : 0)  (in-place on acc) ------
__global__ __launch_bounds__(256) void finalizeB(
    float* __restrict__ acc, const float* __restrict__ pe2,
    const float* __restrict__ b2, const float* __restrict__ cnt, int M)
{
    int gid = blockIdx.x * 256 + threadIdx.x;
    int e = gid >> 5;
    if (e >= M) return;
    int c = (gid & 31) * 4;
    float cn = cnt[e];
    float rs = 1.0f / fmaxf(cn, 1.0f);
    float on = (cn > 0.5f) ? 1.0f : 0.0f;
    float4 a = *(float4*)(acc + (size_t)e * D + c);
    float4 p = *(const float4*)(pe2 + (size_t)e * D + c);
    float4 b = *(const float4*)(b2 + c);
    a.x = a.x * rs + on * (p.x + b.x);
    a.y = a.y * rs + on * (p.y + b.y);
    a.z = a.z * rs + on * (p.z + b.z);
    a.w = a.w * rs + on * (p.w + b.w);
    *(float4*)(acc + (size_t)e * D + c) = a;
}

// ---------------- ef3 = acc/max(cnt,1) + B  (in-place on acc) ----------------------------
__global__ __launch_bounds__(256) void finalize_ef3(
    float* __restrict__ acc, const float* __restrict__ B,
    const float* __restrict__ cnt, int M)
{
    int gid = blockIdx.x * 256 + threadIdx.x;
    int e = gid >> 5;
    if (e >= M) return;
    int c = (gid & 31) * 4;
    float rs = 1.0f / fmaxf(cnt[e], 1.0f);
    float4 a = *(float4*)(acc + (size_t)e * D + c);
    float4 b = *(const float4*)(B + (size_t)e * D + c);
    a.x = a.x * rs + b.x;
    a.y = a.y * rs + b.y;
    a.z = a.z * rs + b.z;
    a.w = a.w * rs + b.w;
    *(float4*)(acc + (size_t)e * D + c) = a;
}

extern "C" void kernel_launch(void* const* d_in, const int* in_sizes, int n_in,
                              void* d_out, int out_size, void* d_ws, size_t ws_size,
                              hipStream_t stream) {
    const float* vfeat  = (const float*)d_in[0];
    const float* efeat  = (const float*)d_in[1];
    const float* invDV  = (const float*)d_in[2];
    const float* invDE  = (const float*)d_in[3];
    const int*   inc_v  = (const int*)d_in[4];
    const int*   inc_e  = (const int*)d_in[5];
    const int*   eM_row = (const int*)d_in[6];
    const int*   eM_col = (const int*)d_in[7];
    const float* eM_val = (const float*)d_in[8];
    const int*   vM_row = (const int*)d_in[9];
    const int*   vM_col = (const int*)d_in[10];
    const float* vM_val = (const float*)d_in[11];
    const float* W_psi1 = (const float*)d_in[12];
    const float* b_psi1 = (const float*)d_in[13];
    const float* W_psi2 = (const float*)d_in[14];
    const float* b_psi2 = (const float*)d_in[15];
    const float* W_v    = (const float*)d_in[16];
    const float* W_e    = (const float*)d_in[17];

    const int N = in_sizes[0] / D;
    const int M = in_sizes[1] / D;
    const int E = in_sizes[4];
    const int nnzE = in_sizes[6];
    const int nnzV = in_sizes[9];

    float* out = (float*)d_out;
    float* vfeat_new = out;                     // N*D
    float* efeat_new = out + (size_t)N * D;     // M*D

    // workspace layout (floats): cntV[N] cntE[M] sdvE[M] bufN1[N*D] bufN2[N*D] bufM1[M*D] bufM2[M*D]
    float* ws    = (float*)d_ws;
    float* cntV  = ws;
    float* cntE  = cntV + N;
    float* sdvE  = cntE + M;
    float* bufN1 = sdvE + M;
    float* bufN2 = bufN1 + (size_t)N * D;
    float* bufM1 = bufN2 + (size_t)N * D;
    float* bufM2 = bufM1 + (size_t)M * D;

    auto cdiv = [](int a, int b) { return (a + b - 1) / b; };
    const dim3 TB(256);
    const size_t ND4 = (size_t)N * D * 4, MD4 = (size_t)M * D * 4;

    // 1. counts (cntV,cntE,sdvE contiguous -> one memset)
    hipMemsetAsync(cntV, 0, (size_t)(N + 2 * M) * 4, stream);
    count_kernel<<<cdiv(E, 256), TB, 0, stream>>>(inc_v, inc_e, invDV, cntV, cntE, sdvE, E);

    // 2. pv1 = vfeat @ W1v^T -> bufN1 ; pe1 = efeat @ W1e^T -> bufM1
    gemm_xwt<<<cdiv(N, 64), TB, 0, stream>>>(vfeat, W_psi1, 2 * D, 0, nullptr, bufN1, N, 0);
    gemm_xwt<<<cdiv(M, 64), TB, 0, stream>>>(efeat, W_psi1, 2 * D, D, nullptr, bufM1, M, 0);

    // 3. A: acc_e += pv1[v]*invDV[v]; A = (acc + (pe1+b1)*sdv)/max(cnt,1)   -> bufM2
    hipMemsetAsync(bufM2, 0, MD4, stream);
    seg_accum<<<cdiv(E * 32, 256), TB, 0, stream>>>(bufN1, inc_v, inc_e, invDV, bufM2, E);
    finalizeA<<<cdiv(M * 32, 256), TB, 0, stream>>>(bufM2, bufM1, b_psi1, sdvE, cntE, M);

    // 4. A <- spmm_E(A); _efeat = A + efeat     -> bufM1
    hipMemsetAsync(bufM1, 0, MD4, stream);
    spmm_accum<<<cdiv(nnzE * 32, 256), TB, 0, stream>>>(bufM2, eM_row, eM_col, eM_val, nullptr, bufM1, nnzE);
    add_inplace<<<cdiv(M * 32, 256), TB, 0, stream>>>(bufM1, efeat, M * 32);

    // 5. _vfeat sum: acc_v += _efeat[e]         -> bufN2  (mean folded into next GEMM)
    hipMemsetAsync(bufN2, 0, ND4, stream);
    seg_accum<<<cdiv(E * 32, 256), TB, 0, stream>>>(bufM1, inc_e, inc_v, nullptr, bufN2, E);

    // 6. vfeat_new = relu((_vfeat/max(cntV,1)) @ W_v^T) -> d_out
    gemm_xwt<<<cdiv(N, 64), TB, 0, stream>>>(bufN2, W_v, D, 0, cntV, vfeat_new, N, 1);

    // 7. pv2 = vfeat_new @ W2v^T -> bufN1 ; pe2 = efeat @ W2e^T -> bufM2
    gemm_xwt<<<cdiv(N, 64), TB, 0, stream>>>(vfeat_new, W_psi2, 2 * D, 0, nullptr, bufN1, N, 0);
    gemm_xwt<<<cdiv(M, 64), TB, 0, stream>>>(efeat, W_psi2, 2 * D, D, nullptr, bufM2, M, 0);

    // 8. B: acc_e += pv2[v]; B = acc/max(cnt,1) + [cnt>0](pe2+b2)   -> bufM1
    hipMemsetAsync(bufM1, 0, MD4, stream);
    seg_accum<<<cdiv(E * 32, 256), TB, 0, stream>>>(bufN1, inc_v, inc_e, nullptr, bufM1, E);
    finalizeB<<<cdiv(M * 32, 256), TB, 0, stream>>>(bufM1, bufM2, b_psi2, cntE, M);

    // 9. _vf2 pre: acc_v += efeat[e]*invDE[e]   -> bufN2 (mean folded into spmm col-scale)
    hipMemsetAsync(bufN2, 0, ND4, stream);
    seg_accum<<<cdiv(E * 32, 256), TB, 0, stream>>>(efeat, inc_e, inc_v, invDE, bufN2, E);

    // 10. _vf2 = spmm_V(_vf2pre/max(cntV,1))    -> bufN1
    hipMemsetAsync(bufN1, 0, ND4, stream);
    spmm_accum<<<cdiv(nnzV * 32, 256), TB, 0, stream>>>(bufN2, vM_row, vM_col, vM_val, cntV, bufN1, nnzV);

    // 11. _ef3: acc_e += _vf2[v]; _ef3 = acc/max(cnt,1) + B   -> bufM2
    hipMemsetAsync(bufM2, 0, MD4, stream);
    seg_accum<<<cdiv(E * 32, 256), TB, 0, stream>>>(bufN1, inc_v, inc_e, nullptr, bufM2, E);
    finalize_ef3<<<cdiv(M * 32, 256), TB, 0, stream>>>(bufM2, bufM1, cntE, M);

    // 12. efeat_new = relu(_ef3 @ W_e^T) -> d_out + N*D
    gemm_xwt<<<cdiv(M, 64), TB, 0, stream>>>(bufM2, W_e, D, 0, nullptr, efeat_new, M, 1);
}

// Round 2
// 1287.954 us; speedup vs baseline: 4.6760x; 4.6760x over previous
//
#include <hip/hip_runtime.h>

#define D 128

// ---------------- GEMM: out[r,i] = act( scale_r * sum_j X[r,j] * W[i*ldw+woff+j] ) --------
__global__ __launch_bounds__(256) void gemm_xwt(
    const float* __restrict__ X, const float* __restrict__ W,
    int ldw, int woff, const float* __restrict__ cntscale,
    float* __restrict__ out, int R, int doRelu)
{
    __shared__ float Ws[D * D];   // 64 KB
    const int t = threadIdx.x;
    for (int idx = t; idx < D * D; idx += 256) {
        int i = idx >> 7, j = idx & (D - 1);
        Ws[j * D + (i ^ (j & 31))] = W[i * ldw + woff + j];
    }
    __syncthreads();
    const int lane = t & 63, wave = t >> 6;
    for (int it = 0; it < 4; ++it) {
        int r0 = blockIdx.x * 64 + it * 16 + wave * 4;
        if (r0 >= R) break;
        int r[4];
#pragma unroll
        for (int rr = 0; rr < 4; ++rr) r[rr] = min(r0 + rr, R - 1);
        float acc[4][2] = {};
        const float4* x0 = (const float4*)(X + (size_t)r[0] * D);
        const float4* x1 = (const float4*)(X + (size_t)r[1] * D);
        const float4* x2 = (const float4*)(X + (size_t)r[2] * D);
        const float4* x3 = (const float4*)(X + (size_t)r[3] * D);
        for (int j4 = 0; j4 < D / 4; ++j4) {
            float4 xa = x0[j4], xb = x1[j4], xc = x2[j4], xd = x3[j4];
#pragma unroll
            for (int jj = 0; jj < 4; ++jj) {
                int j = j4 * 4 + jj;
                int sw = j & 31;
                float w0 = Ws[j * D + (lane ^ sw)];
                float w1 = Ws[j * D + ((lane + 64) ^ sw)];
                float va = (jj == 0) ? xa.x : (jj == 1) ? xa.y : (jj == 2) ? xa.z : xa.w;
                float vb = (jj == 0) ? xb.x : (jj == 1) ? xb.y : (jj == 2) ? xb.z : xb.w;
                float vc = (jj == 0) ? xc.x : (jj == 1) ? xc.y : (jj == 2) ? xc.z : xc.w;
                float vd = (jj == 0) ? xd.x : (jj == 1) ? xd.y : (jj == 2) ? xd.z : xd.w;
                acc[0][0] += va * w0; acc[0][1] += va * w1;
                acc[1][0] += vb * w0; acc[1][1] += vb * w1;
                acc[2][0] += vc * w0; acc[2][1] += vc * w1;
                acc[3][0] += vd * w0; acc[3][1] += vd * w1;
            }
        }
#pragma unroll
        for (int rr = 0; rr < 4; ++rr) {
            int rw = r0 + rr;
            if (rw >= R) break;
            float s = cntscale ? (1.0f / fmaxf(cntscale[rw], 1.0f)) : 1.0f;
            float v0 = acc[rr][0] * s, v1 = acc[rr][1] * s;
            if (doRelu) { v0 = fmaxf(v0, 0.0f); v1 = fmaxf(v1, 0.0f); }
            out[(size_t)rw * D + lane] = v0;
            out[(size_t)rw * D + 64 + lane] = v1;
        }
    }
}

// ---------------- counting-sort building blocks ------------------------------------------
__global__ __launch_bounds__(256) void hist_kernel(
    const int* __restrict__ keys, int n, int* __restrict__ cnt)
{
    int i = blockIdx.x * 256 + threadIdx.x;
    if (i < n) atomicAdd(&cnt[keys[i]], 1);
}

__global__ __launch_bounds__(256) void scatter_kernel(
    const int* __restrict__ keys, int n, const int* __restrict__ off,
    int* __restrict__ cur, int* __restrict__ slots)
{
    int i = blockIdx.x * 256 + threadIdx.x;
    if (i >= n) return;
    int key = keys[i];
    int pos = off[key] + atomicAdd(&cur[key], 1);
    slots[pos] = i;
}

// single-block chunked exclusive scan; out has n+1 entries (out[n] = total)
__global__ __launch_bounds__(1024) void exscan_kernel(
    const int* __restrict__ in, int* __restrict__ out, int n)
{
    __shared__ int wsum[16];
    __shared__ int wpre[17];
    __shared__ int carry;
    const int t = threadIdx.x, wid = t >> 6, lane = t & 63;
    if (t == 0) carry = 0;
    __syncthreads();
    for (int base = 0; base < n; base += 1024) {
        int x = (base + t < n) ? in[base + t] : 0;
        int v = x;
#pragma unroll
        for (int of = 1; of < 64; of <<= 1) {
            int u = __shfl_up(v, of, 64);
            if (lane >= of) v += u;
        }
        if (lane == 63) wsum[wid] = v;
        __syncthreads();
        if (t == 0) {
            int s = carry;
#pragma unroll
            for (int i = 0; i < 16; ++i) { wpre[i] = s; s += wsum[i]; }
            wpre[16] = s;
        }
        __syncthreads();
        if (base + t < n) out[base + t] = wpre[wid] + v - x;
        __syncthreads();
        if (t == 0) carry = wpre[16];
        __syncthreads();
    }
    if (t == 0) out[n] = carry;
}

// ---------------- CSR gather segment-reduce ----------------------------------------------
// One wave per dst row r; lane owns 2 columns (float2).
// per-slot: k = slots[s]; gs = gmap[k]; w = sval?sval[k] : (gscale?gscale[gs]:1)
// acc += src[gs]*w ; sd += w
// FIN 0: dst = acc (+aux[r] if aux)
// FIN 1: dst = acc / max(cnt,1)
// FIN 2: dst = acc/max(cnt,1) + (cnt>0 ? aux[r]+bias : 0)
// FIN 3: dst = acc/max(cnt,1) + aux[r]
// FIN 4: dst = (acc + (aux[r]+bias)*sd) / max(cnt,1)
template<int FIN>
__global__ __launch_bounds__(256) void seg_gather(
    const float* __restrict__ src, const int* __restrict__ off,
    const int* __restrict__ slots, const int* __restrict__ gmap,
    const float* __restrict__ gscale, const float* __restrict__ sval,
    const float* __restrict__ aux, const float* __restrict__ bias,
    float* __restrict__ dst, int R)
{
    int r = blockIdx.x * 4 + (threadIdx.x >> 6);
    if (r >= R) return;
    const int lane = threadIdx.x & 63;
    const int s0 = off[r], s1 = off[r + 1];
    float2 acc = {0.0f, 0.0f};
    float sd = 0.0f;
    for (int base = s0; base < s1; base += 64) {
        int nchunk = min(64, s1 - base);
        int myk = 0, mygs = 0;
        float myw = 1.0f;
        if (base + lane < s1) {
            myk = slots[base + lane];
            mygs = gmap[myk];
            if (sval) myw = sval[myk];
            else if (gscale) myw = gscale[mygs];
        }
        for (int j = 0; j < nchunk; ++j) {
            int gs = __shfl(mygs, j, 64);
            float w = __shfl(myw, j, 64);
            float2 v = *(const float2*)(src + (size_t)gs * D + lane * 2);
            acc.x += v.x * w;
            acc.y += v.y * w;
            if (FIN == 4) sd += w;
        }
    }
    const int cnt = s1 - s0;
    const float rs = 1.0f / (float)max(cnt, 1);
    float2 o = acc;
    if (FIN == 1) { o.x *= rs; o.y *= rs; }
    else if (FIN == 0) {
        if (aux) {
            float2 a = *(const float2*)(aux + (size_t)r * D + lane * 2);
            o.x += a.x; o.y += a.y;
        }
    } else if (FIN == 2) {
        float2 a = *(const float2*)(aux + (size_t)r * D + lane * 2);
        float2 b = *(const float2*)(bias + lane * 2);
        float on = (cnt > 0) ? 1.0f : 0.0f;
        o.x = o.x * rs + on * (a.x + b.x);
        o.y = o.y * rs + on * (a.y + b.y);
    } else if (FIN == 3) {
        float2 a = *(const float2*)(aux + (size_t)r * D + lane * 2);
        o.x = o.x * rs + a.x;
        o.y = o.y * rs + a.y;
    } else if (FIN == 4) {
        float2 a = *(const float2*)(aux + (size_t)r * D + lane * 2);
        float2 b = *(const float2*)(bias + lane * 2);
        o.x = (o.x + (a.x + b.x) * sd) * rs;
        o.y = (o.y + (a.y + b.y) * sd) * rs;
    }
    *(float2*)(dst + (size_t)r * D + lane * 2) = o;
}

extern "C" void kernel_launch(void* const* d_in, const int* in_sizes, int n_in,
                              void* d_out, int out_size, void* d_ws, size_t ws_size,
                              hipStream_t stream) {
    const float* vfeat  = (const float*)d_in[0];
    const float* efeat  = (const float*)d_in[1];
    const float* invDV  = (const float*)d_in[2];
    const float* invDE  = (const float*)d_in[3];
    const int*   inc_v  = (const int*)d_in[4];
    const int*   inc_e  = (const int*)d_in[5];
    const int*   eM_row = (const int*)d_in[6];
    const int*   eM_col = (const int*)d_in[7];
    const float* eM_val = (const float*)d_in[8];
    const int*   vM_row = (const int*)d_in[9];
    const int*   vM_col = (const int*)d_in[10];
    const float* vM_val = (const float*)d_in[11];
    const float* W_psi1 = (const float*)d_in[12];
    const float* b_psi1 = (const float*)d_in[13];
    const float* W_psi2 = (const float*)d_in[14];
    const float* b_psi2 = (const float*)d_in[15];
    const float* W_v    = (const float*)d_in[16];
    const float* W_e    = (const float*)d_in[17];

    const int N = in_sizes[0] / D;
    const int M = in_sizes[1] / D;
    const int E = in_sizes[4];
    const int nnzE = in_sizes[6];
    const int nnzV = in_sizes[9];

    float* out = (float*)d_out;
    float* vfeat_new = out;                     // N*D
    float* efeat_new = out + (size_t)N * D;     // M*D

    // workspace layout
    float* ws    = (float*)d_ws;
    float* bufN1 = ws;
    float* bufN2 = bufN1 + (size_t)N * D;
    float* bufM1 = bufN2 + (size_t)N * D;
    float* bufM2 = bufM1 + (size_t)M * D;
    int* ip      = (int*)(bufM2 + (size_t)M * D);
    int* offE    = ip;              ip += M + 1;
    int* offV    = ip;              ip += N + 1;
    int* offEr   = ip;              ip += M + 1;
    int* offVr   = ip;              ip += N + 1;
    int* slotsE  = ip;              ip += E;
    int* slotsV  = ip;              ip += E;
    int* slotsEr = ip;              ip += nnzE;
    int* slotsVr = ip;              ip += nnzV;
    int* tmp     = ip;              // max(N,M) ints

    auto cdiv = [](int a, int b) { return (a + b - 1) / b; };
    const dim3 TB(256);

    // ---- build 4 CSR orderings (counting sorts) ----
    struct Sort { const int* keys; int n; int R; int* off; int* slots; };
    Sort sorts[4] = {
        { inc_e,  E,    M, offE,  slotsE  },
        { inc_v,  E,    N, offV,  slotsV  },
        { eM_row, nnzE, M, offEr, slotsEr },
        { vM_row, nnzV, N, offVr, slotsVr },
    };
    for (int s = 0; s < 4; ++s) {
        hipMemsetAsync(tmp, 0, (size_t)sorts[s].R * 4, stream);
        hist_kernel<<<cdiv(sorts[s].n, 256), TB, 0, stream>>>(sorts[s].keys, sorts[s].n, tmp);
        exscan_kernel<<<1, 1024, 0, stream>>>(tmp, sorts[s].off, sorts[s].R);
        hipMemsetAsync(tmp, 0, (size_t)sorts[s].R * 4, stream);
        scatter_kernel<<<cdiv(sorts[s].n, 256), TB, 0, stream>>>(
            sorts[s].keys, sorts[s].n, sorts[s].off, tmp, sorts[s].slots);
    }

    // ---- dense pipeline ----
    // pv1 = vfeat @ W1v^T -> bufN1 ; pe1 = efeat @ W1e^T -> bufM1
    gemm_xwt<<<cdiv(N, 64), TB, 0, stream>>>(vfeat, W_psi1, 2 * D, 0, nullptr, bufN1, N, 0);
    gemm_xwt<<<cdiv(M, 64), TB, 0, stream>>>(efeat, W_psi1, 2 * D, D, nullptr, bufM1, M, 0);

    // A[e] = (sum pv1[v]*invDV[v] + (pe1[e]+b1)*sum invDV[v]) / max(cnt,1)  -> bufM2
    seg_gather<4><<<cdiv(M, 4), TB, 0, stream>>>(
        bufN1, offE, slotsE, inc_v, invDV, nullptr, bufM1, b_psi1, bufM2, M);

    // _efeat = spmm_E(A) + efeat -> bufM1
    seg_gather<0><<<cdiv(M, 4), TB, 0, stream>>>(
        bufM2, offEr, slotsEr, eM_col, nullptr, eM_val, efeat, nullptr, bufM1, M);

    // _vfeat = mean_v(_efeat[inc_e]) -> bufN2
    seg_gather<1><<<cdiv(N, 4), TB, 0, stream>>>(
        bufM1, offV, slotsV, inc_e, nullptr, nullptr, nullptr, nullptr, bufN2, N);

    // vfeat_new = relu(_vfeat @ W_v^T) -> d_out
    gemm_xwt<<<cdiv(N, 64), TB, 0, stream>>>(bufN2, W_v, D, 0, nullptr, vfeat_new, N, 1);

    // pv2 = vfeat_new @ W2v^T -> bufN1 ; pe2 = efeat @ W2e^T -> bufM2
    gemm_xwt<<<cdiv(N, 64), TB, 0, stream>>>(vfeat_new, W_psi2, 2 * D, 0, nullptr, bufN1, N, 0);
    gemm_xwt<<<cdiv(M, 64), TB, 0, stream>>>(efeat, W_psi2, 2 * D, D, nullptr, bufM2, M, 0);

    // B[e] = mean(pv2[v]) + [cnt>0](pe2[e]+b2) -> bufM1
    seg_gather<2><<<cdiv(M, 4), TB, 0, stream>>>(
        bufN1, offE, slotsE, inc_v, nullptr, nullptr, bufM2, b_psi2, bufM1, M);

    // _vf2pre = mean_v(efeat[inc_e]*invDE[inc_e]) -> bufN2
    seg_gather<1><<<cdiv(N, 4), TB, 0, stream>>>(
        efeat, offV, slotsV, inc_e, invDE, nullptr, nullptr, nullptr, bufN2, N);

    // _vf2 = spmm_V(_vf2pre) -> bufN1
    seg_gather<0><<<cdiv(N, 4), TB, 0, stream>>>(
        bufN2, offVr, slotsVr, vM_col, nullptr, vM_val, nullptr, nullptr, bufN1, N);

    // _ef3 = mean_e(_vf2[inc_v]) + B -> bufM2
    seg_gather<3><<<cdiv(M, 4), TB, 0, stream>>>(
        bufN1, offE, slotsE, inc_v, nullptr, nullptr, bufM1, nullptr, bufM2, M);

    // efeat_new = relu(_ef3 @ W_e^T) -> d_out + N*D
    gemm_xwt<<<cdiv(M, 64), TB, 0, stream>>>(bufM2, W_e, D, 0, nullptr, efeat_new, M, 1);
}

// Round 3
// 841.904 us; speedup vs baseline: 7.1534x; 1.5298x over previous
//
#include <hip/hip_runtime.h>

#define D 128

typedef __bf16 bf16;
typedef __attribute__((ext_vector_type(8))) __bf16 bf16x8;
typedef __attribute__((ext_vector_type(4))) float f32x4;

// ---------------- MFMA GEMM: out[r,i] = act( scale_r * sum_j X[r,j] * W[i*ldw+woff+j] ) ---
// X (R x 128) fp32 -> bf16 in-register; W (128 x 128 slice) staged in LDS as bf16 with
// 16B-block XOR swizzle so fragment ds_read_b128 is conflict-free.
// Block: 256 threads = 4 waves; each wave computes 32 rows x 128 cols; block = 128 rows.
__global__ __launch_bounds__(256) void gemm_mfma(
    const float* __restrict__ X, const float* __restrict__ W,
    int ldw, int woff, const float* __restrict__ cntscale,
    float* __restrict__ out, int R, int doRelu)
{
    __shared__ __align__(16) bf16 Ws[D * D];   // 32 KB
    const int t = threadIdx.x;
    // stage W: 128 rows x 16 blocks of 8 elems; swizzle blk ^= row&15
    for (int g = t; g < D * 16; g += 256) {
        int row = g >> 4, blk = g & 15;
        const float* src = W + (size_t)row * ldw + woff + blk * 8;
        float4 f0 = *(const float4*)(src);
        float4 f1 = *(const float4*)(src + 4);
        bf16x8 v = { (bf16)f0.x, (bf16)f0.y, (bf16)f0.z, (bf16)f0.w,
                     (bf16)f1.x, (bf16)f1.y, (bf16)f1.z, (bf16)f1.w };
        int sblk = blk ^ (row & 15);
        *(bf16x8*)(&Ws[row * D + sblk * 8]) = v;
    }
    __syncthreads();

    const int lane = t & 63, wave = t >> 6;
    const int lrow = lane & 15, lk8 = lane >> 4;   // fragment row / k-subblock
    const int r0 = blockIdx.x * 128 + wave * 32;

    f32x4 acc[2][8] = {};
    for (int ks = 0; ks < 4; ++ks) {
        bf16x8 a[2];
#pragma unroll
        for (int mf = 0; mf < 2; ++mf) {
            int r = r0 + mf * 16 + lrow;
            if (r > R - 1) r = R - 1;
            const float* xs = X + (size_t)r * D + ks * 32 + lk8 * 8;
            float4 f0 = *(const float4*)(xs);
            float4 f1 = *(const float4*)(xs + 4);
            a[mf] = (bf16x8){ (bf16)f0.x, (bf16)f0.y, (bf16)f0.z, (bf16)f0.w,
                              (bf16)f1.x, (bf16)f1.y, (bf16)f1.z, (bf16)f1.w };
        }
        bf16x8 b[8];
#pragma unroll
        for (int nf = 0; nf < 8; ++nf) {
            int row = nf * 16 + lrow;
            int blk = ks * 4 + lk8;
            b[nf] = *(const bf16x8*)(&Ws[row * D + (blk ^ (row & 15)) * 8]);
        }
#pragma unroll
        for (int mf = 0; mf < 2; ++mf)
#pragma unroll
            for (int nf = 0; nf < 8; ++nf)
                acc[mf][nf] = __builtin_amdgcn_mfma_f32_16x16x32_bf16(a[mf], b[nf], acc[mf][nf], 0, 0, 0);
    }

    // epilogue: C/D layout col=lane&15, row=(lane>>4)*4+e  [verified mapping]
#pragma unroll
    for (int mf = 0; mf < 2; ++mf) {
        int rbase = r0 + mf * 16 + (lane >> 4) * 4;
#pragma unroll
        for (int e = 0; e < 4; ++e) {
            int r = rbase + e;
            if (r >= R) continue;
            float s = cntscale ? (1.0f / fmaxf(cntscale[r], 1.0f)) : 1.0f;
#pragma unroll
            for (int nf = 0; nf < 8; ++nf) {
                float v = acc[mf][nf][e] * s;
                if (doRelu) v = fmaxf(v, 0.0f);
                out[(size_t)r * D + nf * 16 + (lane & 15)] = v;
            }
        }
    }
}

// ---------------- counting-sort building blocks ------------------------------------------
__global__ __launch_bounds__(256) void hist_kernel(
    const int* __restrict__ keys, int n, int* __restrict__ cnt)
{
    int i = blockIdx.x * 256 + threadIdx.x;
    if (i < n) atomicAdd(&cnt[keys[i]], 1);
}

__global__ __launch_bounds__(256) void scatter_kernel(
    const int* __restrict__ keys, int n, const int* __restrict__ off,
    int* __restrict__ cur, int* __restrict__ slots)
{
    int i = blockIdx.x * 256 + threadIdx.x;
    if (i >= n) return;
    int key = keys[i];
    int pos = off[key] + atomicAdd(&cur[key], 1);
    slots[pos] = i;
}

// single-block chunked exclusive scan; out has n+1 entries (out[n] = total)
__global__ __launch_bounds__(1024) void exscan_kernel(
    const int* __restrict__ in, int* __restrict__ out, int n)
{
    __shared__ int wsum[16];
    __shared__ int wpre[17];
    __shared__ int carry;
    const int t = threadIdx.x, wid = t >> 6, lane = t & 63;
    if (t == 0) carry = 0;
    __syncthreads();
    for (int base = 0; base < n; base += 1024) {
        int x = (base + t < n) ? in[base + t] : 0;
        int v = x;
#pragma unroll
        for (int of = 1; of < 64; of <<= 1) {
            int u = __shfl_up(v, of, 64);
            if (lane >= of) v += u;
        }
        if (lane == 63) wsum[wid] = v;
        __syncthreads();
        if (t == 0) {
            int s = carry;
#pragma unroll
            for (int i = 0; i < 16; ++i) { wpre[i] = s; s += wsum[i]; }
            wpre[16] = s;
        }
        __syncthreads();
        if (base + t < n) out[base + t] = wpre[wid] + v - x;
        __syncthreads();
        if (t == 0) carry = wpre[16];
        __syncthreads();
    }
    if (t == 0) out[n] = carry;
}

// ---------------- CSR gather segment-reduce ----------------------------------------------
// One wave per dst row r; lane owns 2 columns (float2).
// per-slot: k = slots[s]; gs = gmap[k]; w = sval?sval[k] : (gscale?gscale[gs]:1)
// FIN 0: dst = acc (+aux[r] if aux)
// FIN 1: dst = acc / max(cnt,1)
// FIN 2: dst = acc/max(cnt,1) + (cnt>0 ? aux[r]+bias : 0)
// FIN 3: dst = acc/max(cnt,1) + aux[r]
// FIN 4: dst = (acc + (aux[r]+bias)*sd) / max(cnt,1)
template<int FIN>
__global__ __launch_bounds__(256) void seg_gather(
    const float* __restrict__ src, const int* __restrict__ off,
    const int* __restrict__ slots, const int* __restrict__ gmap,
    const float* __restrict__ gscale, const float* __restrict__ sval,
    const float* __restrict__ aux, const float* __restrict__ bias,
    float* __restrict__ dst, int R)
{
    int r = blockIdx.x * 4 + (threadIdx.x >> 6);
    if (r >= R) return;
    const int lane = threadIdx.x & 63;
    const int s0 = off[r], s1 = off[r + 1];
    float2 acc = {0.0f, 0.0f};
    float sd = 0.0f;
    for (int base = s0; base < s1; base += 64) {
        int nchunk = min(64, s1 - base);
        int myk = 0, mygs = 0;
        float myw = 1.0f;
        if (base + lane < s1) {
            myk = slots[base + lane];
            mygs = gmap[myk];
            if (sval) myw = sval[myk];
            else if (gscale) myw = gscale[mygs];
        }
        for (int j = 0; j < nchunk; ++j) {
            int gs = __shfl(mygs, j, 64);
            float w = __shfl(myw, j, 64);
            float2 v = *(const float2*)(src + (size_t)gs * D + lane * 2);
            acc.x += v.x * w;
            acc.y += v.y * w;
            if (FIN == 4) sd += w;
        }
    }
    const int cnt = s1 - s0;
    const float rs = 1.0f / (float)max(cnt, 1);
    float2 o = acc;
    if (FIN == 1) { o.x *= rs; o.y *= rs; }
    else if (FIN == 0) {
        if (aux) {
            float2 a = *(const float2*)(aux + (size_t)r * D + lane * 2);
            o.x += a.x; o.y += a.y;
        }
    } else if (FIN == 2) {
        float2 a = *(const float2*)(aux + (size_t)r * D + lane * 2);
        float2 b = *(const float2*)(bias + lane * 2);
        float on = (cnt > 0) ? 1.0f : 0.0f;
        o.x = o.x * rs + on * (a.x + b.x);
        o.y = o.y * rs + on * (a.y + b.y);
    } else if (FIN == 3) {
        float2 a = *(const float2*)(aux + (size_t)r * D + lane * 2);
        o.x = o.x * rs + a.x;
        o.y = o.y * rs + a.y;
    } else if (FIN == 4) {
        float2 a = *(const float2*)(aux + (size_t)r * D + lane * 2);
        float2 b = *(const float2*)(bias + lane * 2);
        o.x = (o.x + (a.x + b.x) * sd) * rs;
        o.y = (o.y + (a.y + b.y) * sd) * rs;
    }
    *(float2*)(dst + (size_t)r * D + lane * 2) = o;
}

extern "C" void kernel_launch(void* const* d_in, const int* in_sizes, int n_in,
                              void* d_out, int out_size, void* d_ws, size_t ws_size,
                              hipStream_t stream) {
    const float* vfeat  = (const float*)d_in[0];
    const float* efeat  = (const float*)d_in[1];
    const float* invDV  = (const float*)d_in[2];
    const float* invDE  = (const float*)d_in[3];
    const int*   inc_v  = (const int*)d_in[4];
    const int*   inc_e  = (const int*)d_in[5];
    const int*   eM_row = (const int*)d_in[6];
    const int*   eM_col = (const int*)d_in[7];
    const float* eM_val = (const float*)d_in[8];
    const int*   vM_row = (const int*)d_in[9];
    const int*   vM_col = (const int*)d_in[10];
    const float* vM_val = (const float*)d_in[11];
    const float* W_psi1 = (const float*)d_in[12];
    const float* b_psi1 = (const float*)d_in[13];
    const float* W_psi2 = (const float*)d_in[14];
    const float* b_psi2 = (const float*)d_in[15];
    const float* W_v    = (const float*)d_in[16];
    const float* W_e    = (const float*)d_in[17];

    const int N = in_sizes[0] / D;
    const int M = in_sizes[1] / D;
    const int E = in_sizes[4];
    const int nnzE = in_sizes[6];
    const int nnzV = in_sizes[9];

    float* out = (float*)d_out;
    float* vfeat_new = out;                     // N*D
    float* efeat_new = out + (size_t)N * D;     // M*D

    // workspace layout
    float* ws    = (float*)d_ws;
    float* bufN1 = ws;
    float* bufN2 = bufN1 + (size_t)N * D;
    float* bufM1 = bufN2 + (size_t)N * D;
    float* bufM2 = bufM1 + (size_t)M * D;
    int* ip      = (int*)(bufM2 + (size_t)M * D);
    int* offE    = ip;              ip += M + 1;
    int* offV    = ip;              ip += N + 1;
    int* offEr   = ip;              ip += M + 1;
    int* offVr   = ip;              ip += N + 1;
    int* slotsE  = ip;              ip += E;
    int* slotsV  = ip;              ip += E;
    int* slotsEr = ip;              ip += nnzE;
    int* slotsVr = ip;              ip += nnzV;
    int* tmp     = ip;              // max(N,M) ints

    auto cdiv = [](int a, int b) { return (a + b - 1) / b; };
    const dim3 TB(256);

    // ---- build 4 CSR orderings (counting sorts) ----
    struct Sort { const int* keys; int n; int R; int* off; int* slots; };
    Sort sorts[4] = {
        { inc_e,  E,    M, offE,  slotsE  },
        { inc_v,  E,    N, offV,  slotsV  },
        { eM_row, nnzE, M, offEr, slotsEr },
        { vM_row, nnzV, N, offVr, slotsVr },
    };
    for (int s = 0; s < 4; ++s) {
        hipMemsetAsync(tmp, 0, (size_t)sorts[s].R * 4, stream);
        hist_kernel<<<cdiv(sorts[s].n, 256), TB, 0, stream>>>(sorts[s].keys, sorts[s].n, tmp);
        exscan_kernel<<<1, 1024, 0, stream>>>(tmp, sorts[s].off, sorts[s].R);
        hipMemsetAsync(tmp, 0, (size_t)sorts[s].R * 4, stream);
        scatter_kernel<<<cdiv(sorts[s].n, 256), TB, 0, stream>>>(
            sorts[s].keys, sorts[s].n, sorts[s].off, tmp, sorts[s].slots);
    }

    // ---- dense pipeline ----
    // pv1 = vfeat @ W1v^T -> bufN1 ; pe1 = efeat @ W1e^T -> bufM1
    gemm_mfma<<<cdiv(N, 128), TB, 0, stream>>>(vfeat, W_psi1, 2 * D, 0, nullptr, bufN1, N, 0);
    gemm_mfma<<<cdiv(M, 128), TB, 0, stream>>>(efeat, W_psi1, 2 * D, D, nullptr, bufM1, M, 0);

    // A[e] = (sum pv1[v]*invDV[v] + (pe1[e]+b1)*sum invDV[v]) / max(cnt,1)  -> bufM2
    seg_gather<4><<<cdiv(M, 4), TB, 0, stream>>>(
        bufN1, offE, slotsE, inc_v, invDV, nullptr, bufM1, b_psi1, bufM2, M);

    // _efeat = spmm_E(A) + efeat -> bufM1
    seg_gather<0><<<cdiv(M, 4), TB, 0, stream>>>(
        bufM2, offEr, slotsEr, eM_col, nullptr, eM_val, efeat, nullptr, bufM1, M);

    // _vfeat = mean_v(_efeat[inc_e]) -> bufN2
    seg_gather<1><<<cdiv(N, 4), TB, 0, stream>>>(
        bufM1, offV, slotsV, inc_e, nullptr, nullptr, nullptr, nullptr, bufN2, N);

    // vfeat_new = relu(_vfeat @ W_v^T) -> d_out
    gemm_mfma<<<cdiv(N, 128), TB, 0, stream>>>(bufN2, W_v, D, 0, nullptr, vfeat_new, N, 1);

    // pv2 = vfeat_new @ W2v^T -> bufN1 ; pe2 = efeat @ W2e^T -> bufM2
    gemm_mfma<<<cdiv(N, 128), TB, 0, stream>>>(vfeat_new, W_psi2, 2 * D, 0, nullptr, bufN1, N, 0);
    gemm_mfma<<<cdiv(M, 128), TB, 0, stream>>>(efeat, W_psi2, 2 * D, D, nullptr, bufM2, M, 0);

    // B[e] = mean(pv2[v]) + [cnt>0](pe2[e]+b2) -> bufM1
    seg_gather<2><<<cdiv(M, 4), TB, 0, stream>>>(
        bufN1, offE, slotsE, inc_v, nullptr, nullptr, bufM2, b_psi2, bufM1, M);

    // _vf2pre = mean_v(efeat[inc_e]*invDE[inc_e]) -> bufN2
    seg_gather<1><<<cdiv(N, 4), TB, 0, stream>>>(
        efeat, offV, slotsV, inc_e, invDE, nullptr, nullptr, nullptr, bufN2, N);

    // _vf2 = spmm_V(_vf2pre) -> bufN1
    seg_gather<0><<<cdiv(N, 4), TB, 0, stream>>>(
        bufN2, offVr, slotsVr, vM_col, nullptr, vM_val, nullptr, nullptr, bufN1, N);

    // _ef3 = mean_e(_vf2[inc_v]) + B -> bufM2
    seg_gather<3><<<cdiv(M, 4), TB, 0, stream>>>(
        bufN1, offE, slotsE, inc_v, nullptr, nullptr, bufM1, nullptr, bufM2, M);

    // efeat_new = relu(_ef3 @ W_e^T) -> d_out + N*D
    gemm_mfma<<<cdiv(M, 128), TB, 0, stream>>>(bufM2, W_e, D, 0, nullptr, efeat_new, M, 1);
}

// Round 4
// 630.520 us; speedup vs baseline: 9.5516x; 1.3353x over previous
//
#include <hip/hip_runtime.h>

#define D 128
#define SCAN_BLK 2048   // 256 threads * 8 elems

typedef __bf16 bf16;
typedef __attribute__((ext_vector_type(8))) __bf16 bf16x8;
typedef __attribute__((ext_vector_type(4))) float f32x4;

// ---------------- MFMA GEMM: out[r,i] = act( scale_r * sum_j X[r,j] * W[i*ldw+woff+j] ) ---
__global__ __launch_bounds__(256) void gemm_mfma(
    const float* __restrict__ X, const float* __restrict__ W,
    int ldw, int woff, const float* __restrict__ cntscale,
    float* __restrict__ out, int R, int doRelu)
{
    __shared__ __align__(16) bf16 Ws[D * D];   // 32 KB
    const int t = threadIdx.x;
    for (int g = t; g < D * 16; g += 256) {
        int row = g >> 4, blk = g & 15;
        const float* src = W + (size_t)row * ldw + woff + blk * 8;
        float4 f0 = *(const float4*)(src);
        float4 f1 = *(const float4*)(src + 4);
        bf16x8 v = { (bf16)f0.x, (bf16)f0.y, (bf16)f0.z, (bf16)f0.w,
                     (bf16)f1.x, (bf16)f1.y, (bf16)f1.z, (bf16)f1.w };
        int sblk = blk ^ (row & 15);
        *(bf16x8*)(&Ws[row * D + sblk * 8]) = v;
    }
    __syncthreads();

    const int lane = t & 63, wave = t >> 6;
    const int lrow = lane & 15, lk8 = lane >> 4;
    const int r0 = blockIdx.x * 128 + wave * 32;

    f32x4 acc[2][8] = {};
    for (int ks = 0; ks < 4; ++ks) {
        bf16x8 a[2];
#pragma unroll
        for (int mf = 0; mf < 2; ++mf) {
            int r = r0 + mf * 16 + lrow;
            if (r > R - 1) r = R - 1;
            const float* xs = X + (size_t)r * D + ks * 32 + lk8 * 8;
            float4 f0 = *(const float4*)(xs);
            float4 f1 = *(const float4*)(xs + 4);
            a[mf] = (bf16x8){ (bf16)f0.x, (bf16)f0.y, (bf16)f0.z, (bf16)f0.w,
                              (bf16)f1.x, (bf16)f1.y, (bf16)f1.z, (bf16)f1.w };
        }
        bf16x8 b[8];
#pragma unroll
        for (int nf = 0; nf < 8; ++nf) {
            int row = nf * 16 + lrow;
            int blk = ks * 4 + lk8;
            b[nf] = *(const bf16x8*)(&Ws[row * D + (blk ^ (row & 15)) * 8]);
        }
#pragma unroll
        for (int mf = 0; mf < 2; ++mf)
#pragma unroll
            for (int nf = 0; nf < 8; ++nf)
                acc[mf][nf] = __builtin_amdgcn_mfma_f32_16x16x32_bf16(a[mf], b[nf], acc[mf][nf], 0, 0, 0);
    }

#pragma unroll
    for (int mf = 0; mf < 2; ++mf) {
        int rbase = r0 + mf * 16 + (lane >> 4) * 4;
#pragma unroll
        for (int e = 0; e < 4; ++e) {
            int r = rbase + e;
            if (r >= R) continue;
            float s = cntscale ? (1.0f / fmaxf(cntscale[r], 1.0f)) : 1.0f;
#pragma unroll
            for (int nf = 0; nf < 8; ++nf) {
                float v = acc[mf][nf][e] * s;
                if (doRelu) v = fmaxf(v, 0.0f);
                out[(size_t)r * D + nf * 16 + (lane & 15)] = v;
            }
        }
    }
}

// ---------------- counting-sort building blocks ------------------------------------------
__global__ __launch_bounds__(256) void hist_kernel(
    const int* __restrict__ keys, int n, int* __restrict__ cnt)
{
    int i = blockIdx.x * 256 + threadIdx.x;
    if (i < n) atomicAdd(&cnt[keys[i]], 1);
}

// pos is GLOBAL (off contains global slot-space bases)
__global__ __launch_bounds__(256) void scatter_kernel(
    const int* __restrict__ keys, int n, const int* __restrict__ off,
    int* __restrict__ cur, int* __restrict__ slots_all)
{
    int i = blockIdx.x * 256 + threadIdx.x;
    if (i >= n) return;
    int key = keys[i];
    int pos = off[key] + atomicAdd(&cur[key], 1);
    slots_all[pos] = i;
}

// ---------------- batched hierarchical exclusive scan ------------------------------------
__global__ __launch_bounds__(256) void scan_pass1(
    const int* __restrict__ in, int n, int* __restrict__ bsum)
{
    int b = blockIdx.x, t = threadIdx.x;
    int base = b * SCAN_BLK + t * 8;
    int s = 0;
#pragma unroll
    for (int j = 0; j < 8; ++j) { int i = base + j; if (i < n) s += in[i]; }
#pragma unroll
    for (int of = 1; of < 64; of <<= 1) s += __shfl_xor(s, of, 64);
    __shared__ int wsum[4];
    if ((t & 63) == 0) wsum[t >> 6] = s;
    __syncthreads();
    if (t == 0) bsum[b] = wsum[0] + wsum[1] + wsum[2] + wsum[3];
}

__global__ __launch_bounds__(256) void scan_pass2(int* __restrict__ bsum, int nb)
{
    __shared__ int carry, wsum[4], wpre[5];
    int t = threadIdx.x, wid = t >> 6, lane = t & 63;
    if (t == 0) carry = 0;
    __syncthreads();
    for (int base = 0; base < nb; base += 256) {
        int x = (base + t < nb) ? bsum[base + t] : 0;
        int v = x;
#pragma unroll
        for (int of = 1; of < 64; of <<= 1) {
            int u = __shfl_up(v, of, 64);
            if (lane >= of) v += u;
        }
        if (lane == 63) wsum[wid] = v;
        __syncthreads();
        if (t == 0) { int s = carry; for (int i = 0; i < 4; ++i) { wpre[i] = s; s += wsum[i]; } wpre[4] = s; }
        __syncthreads();
        if (base + t < nb) bsum[base + t] = wpre[wid] + v - x;
        __syncthreads();
        if (t == 0) carry = wpre[4];
        __syncthreads();
    }
}

__global__ __launch_bounds__(256) void scan_pass3(
    const int* __restrict__ in, int n, const int* __restrict__ bsum, int* __restrict__ out)
{
    int b = blockIdx.x, t = threadIdx.x, wid = t >> 6, lane = t & 63;
    int base = b * SCAN_BLK + t * 8;
    int x[8], s = 0;
#pragma unroll
    for (int j = 0; j < 8; ++j) { int i = base + j; x[j] = (i < n) ? in[i] : 0; s += x[j]; }
    int v = s;
#pragma unroll
    for (int of = 1; of < 64; of <<= 1) {
        int u = __shfl_up(v, of, 64);
        if (lane >= of) v += u;
    }
    __shared__ int wsum[4], wpre[4];
    if (lane == 63) wsum[wid] = v;
    __syncthreads();
    if (t == 0) { int acc = 0; for (int i = 0; i < 4; ++i) { wpre[i] = acc; acc += wsum[i]; } }
    __syncthreads();
    int pre = bsum[b] + wpre[wid] + (v - s);
#pragma unroll
    for (int j = 0; j < 8; ++j) { int i = base + j; if (i < n) out[i] = pre; pre += x[j]; }
}

// ---------------- CSR gather segment-reduce ----------------------------------------------
// FIN 0: dst = acc (+aux[r] if aux)
// FIN 1: dst = acc / max(cnt,1)
// FIN 2: dst = acc/max(cnt,1) + (cnt>0 ? aux[r]+bias : 0)
// FIN 3: dst = acc/max(cnt,1) + aux[r]
// FIN 4: dst = (acc + (aux[r]+bias)*sd) / max(cnt,1)
template<int FIN>
__global__ __launch_bounds__(256) void seg_gather(
    const float* __restrict__ src, const int* __restrict__ off,
    const int* __restrict__ slots, const int* __restrict__ gmap,
    const float* __restrict__ gscale, const float* __restrict__ sval,
    const float* __restrict__ aux, const float* __restrict__ bias,
    float* __restrict__ dst, int R)
{
    int r = blockIdx.x * 4 + (threadIdx.x >> 6);
    if (r >= R) return;
    const int lane = threadIdx.x & 63;
    const int s0 = off[r], s1 = off[r + 1];
    float2 acc = {0.0f, 0.0f};
    float sd = 0.0f;
    for (int base = s0; base < s1; base += 64) {
        int nchunk = min(64, s1 - base);
        int myk = 0, mygs = 0;
        float myw = 1.0f;
        if (base + lane < s1) {
            myk = slots[base + lane];
            mygs = gmap[myk];
            if (sval) myw = sval[myk];
            else if (gscale) myw = gscale[mygs];
        }
        for (int j = 0; j < nchunk; ++j) {
            int gs = __shfl(mygs, j, 64);
            float w = __shfl(myw, j, 64);
            float2 v = *(const float2*)(src + (size_t)gs * D + lane * 2);
            acc.x += v.x * w;
            acc.y += v.y * w;
            if (FIN == 4) sd += w;
        }
    }
    const int cnt = s1 - s0;
    const float rs = 1.0f / (float)max(cnt, 1);
    float2 o = acc;
    if (FIN == 1) { o.x *= rs; o.y *= rs; }
    else if (FIN == 0) {
        if (aux) {
            float2 a = *(const float2*)(aux + (size_t)r * D + lane * 2);
            o.x += a.x; o.y += a.y;
        }
    } else if (FIN == 2) {
        float2 a = *(const float2*)(aux + (size_t)r * D + lane * 2);
        float2 b = *(const float2*)(bias + lane * 2);
        float on = (cnt > 0) ? 1.0f : 0.0f;
        o.x = o.x * rs + on * (a.x + b.x);
        o.y = o.y * rs + on * (a.y + b.y);
    } else if (FIN == 3) {
        float2 a = *(const float2*)(aux + (size_t)r * D + lane * 2);
        o.x = o.x * rs + a.x;
        o.y = o.y * rs + a.y;
    } else if (FIN == 4) {
        float2 a = *(const float2*)(aux + (size_t)r * D + lane * 2);
        float2 b = *(const float2*)(bias + lane * 2);
        o.x = (o.x + (a.x + b.x) * sd) * rs;
        o.y = (o.y + (a.y + b.y) * sd) * rs;
    }
    *(float2*)(dst + (size_t)r * D + lane * 2) = o;
}

extern "C" void kernel_launch(void* const* d_in, const int* in_sizes, int n_in,
                              void* d_out, int out_size, void* d_ws, size_t ws_size,
                              hipStream_t stream) {
    const float* vfeat  = (const float*)d_in[0];
    const float* efeat  = (const float*)d_in[1];
    const float* invDV  = (const float*)d_in[2];
    const float* invDE  = (const float*)d_in[3];
    const int*   inc_v  = (const int*)d_in[4];
    const int*   inc_e  = (const int*)d_in[5];
    const int*   eM_row = (const int*)d_in[6];
    const int*   eM_col = (const int*)d_in[7];
    const float* eM_val = (const float*)d_in[8];
    const int*   vM_row = (const int*)d_in[9];
    const int*   vM_col = (const int*)d_in[10];
    const float* vM_val = (const float*)d_in[11];
    const float* W_psi1 = (const float*)d_in[12];
    const float* b_psi1 = (const float*)d_in[13];
    const float* W_psi2 = (const float*)d_in[14];
    const float* b_psi2 = (const float*)d_in[15];
    const float* W_v    = (const float*)d_in[16];
    const float* W_e    = (const float*)d_in[17];

    const int N = in_sizes[0] / D;
    const int M = in_sizes[1] / D;
    const int E = in_sizes[4];
    const int nnzE = in_sizes[6];
    const int nnzV = in_sizes[9];

    float* out = (float*)d_out;
    float* vfeat_new = out;                     // N*D
    float* efeat_new = out + (size_t)N * D;     // M*D

    // concatenated segment table: [cntE(M) gap][cntV(N) gap][cntEr(M) gap][cntVr(N) gap]
    const int T = 2 * M + 2 * N + 4;
    const int nbScan = (T + SCAN_BLK - 1) / SCAN_BLK;

    // workspace layout
    float* ws    = (float*)d_ws;
    float* bufN1 = ws;
    float* bufN2 = bufN1 + (size_t)N * D;
    float* bufM1 = bufN2 + (size_t)N * D;
    float* bufM2 = bufM1 + (size_t)M * D;
    int* ip        = (int*)(bufM2 + (size_t)M * D);
    int* off_all   = ip;                 ip += T;
    int* cnt_all   = ip;                 ip += T;   // cnt_all and cur_all adjacent:
    int* cur_all   = ip;                 ip += T;   // one memset covers both
    int* bsum      = ip;                 ip += nbScan + 1;
    int* slots_all = ip;                 // E + E + nnzE + nnzV ints

    int* offE  = off_all;
    int* offV  = offE + (M + 1);
    int* offEr = offV + (N + 1);
    int* offVr = offEr + (M + 1);
    const int bE  = 0;
    const int bV  = M + 1;
    const int bEr = bV + (N + 1);
    const int bVr = bEr + (M + 1);

    auto cdiv = [](int a, int b) { return (a + b - 1) / b; };
    const dim3 TB(256);

    // ---- build all 4 CSR orderings with ONE batched scan ----
    hipMemsetAsync(cnt_all, 0, (size_t)(2 * T) * 4, stream);
    hist_kernel<<<cdiv(E, 256), TB, 0, stream>>>(inc_e,  E,    cnt_all + bE);
    hist_kernel<<<cdiv(E, 256), TB, 0, stream>>>(inc_v,  E,    cnt_all + bV);
    hist_kernel<<<cdiv(nnzE, 256), TB, 0, stream>>>(eM_row, nnzE, cnt_all + bEr);
    hist_kernel<<<cdiv(nnzV, 256), TB, 0, stream>>>(vM_row, nnzV, cnt_all + bVr);
    scan_pass1<<<nbScan, TB, 0, stream>>>(cnt_all, T, bsum);
    scan_pass2<<<1, TB, 0, stream>>>(bsum, nbScan);
    scan_pass3<<<nbScan, TB, 0, stream>>>(cnt_all, T, bsum, off_all);
    scatter_kernel<<<cdiv(E, 256), TB, 0, stream>>>(inc_e,  E,    off_all + bE,  cur_all + bE,  slots_all);
    scatter_kernel<<<cdiv(E, 256), TB, 0, stream>>>(inc_v,  E,    off_all + bV,  cur_all + bV,  slots_all);
    scatter_kernel<<<cdiv(nnzE, 256), TB, 0, stream>>>(eM_row, nnzE, off_all + bEr, cur_all + bEr, slots_all);
    scatter_kernel<<<cdiv(nnzV, 256), TB, 0, stream>>>(vM_row, nnzV, off_all + bVr, cur_all + bVr, slots_all);

    // ---- dense pipeline ----
    // pv1 = vfeat @ W1v^T -> bufN1 ; pe1 = efeat @ W1e^T -> bufM1
    gemm_mfma<<<cdiv(N, 128), TB, 0, stream>>>(vfeat, W_psi1, 2 * D, 0, nullptr, bufN1, N, 0);
    gemm_mfma<<<cdiv(M, 128), TB, 0, stream>>>(efeat, W_psi1, 2 * D, D, nullptr, bufM1, M, 0);

    // A[e] = (sum pv1[v]*invDV[v] + (pe1[e]+b1)*sum invDV[v]) / max(cnt,1)  -> bufM2
    seg_gather<4><<<cdiv(M, 4), TB, 0, stream>>>(
        bufN1, offE, slots_all, inc_v, invDV, nullptr, bufM1, b_psi1, bufM2, M);

    // _efeat = spmm_E(A) + efeat -> bufM1
    seg_gather<0><<<cdiv(M, 4), TB, 0, stream>>>(
        bufM2, offEr, slots_all, eM_col, nullptr, eM_val, efeat, nullptr, bufM1, M);

    // _vfeat = mean_v(_efeat[inc_e]) -> bufN2
    seg_gather<1><<<cdiv(N, 4), TB, 0, stream>>>(
        bufM1, offV, slots_all, inc_e, nullptr, nullptr, nullptr, nullptr, bufN2, N);

    // vfeat_new = relu(_vfeat @ W_v^T) -> d_out
    gemm_mfma<<<cdiv(N, 128), TB, 0, stream>>>(bufN2, W_v, D, 0, nullptr, vfeat_new, N, 1);

    // pv2 = vfeat_new @ W2v^T -> bufN1 ; pe2 = efeat @ W2e^T -> bufM2
    gemm_mfma<<<cdiv(N, 128), TB, 0, stream>>>(vfeat_new, W_psi2, 2 * D, 0, nullptr, bufN1, N, 0);
    gemm_mfma<<<cdiv(M, 128), TB, 0, stream>>>(efeat, W_psi2, 2 * D, D, nullptr, bufM2, M, 0);

    // B[e] = mean(pv2[v]) + [cnt>0](pe2[e]+b2) -> bufM1
    seg_gather<2><<<cdiv(M, 4), TB, 0, stream>>>(
        bufN1, offE, slots_all, inc_v, nullptr, nullptr, bufM2, b_psi2, bufM1, M);

    // _vf2pre = mean_v(efeat[inc_e]*invDE[inc_e]) -> bufN2
    seg_gather<1><<<cdiv(N, 4), TB, 0, stream>>>(
        efeat, offV, slots_all, inc_e, invDE, nullptr, nullptr, nullptr, bufN2, N);

    // _vf2 = spmm_V(_vf2pre) -> bufN1
    seg_gather<0><<<cdiv(N, 4), TB, 0, stream>>>(
        bufN2, offVr, slots_all, vM_col, nullptr, vM_val, nullptr, nullptr, bufN1, N);

    // _ef3 = mean_e(_vf2[inc_v]) + B -> bufM2
    seg_gather<3><<<cdiv(M, 4), TB, 0, stream>>>(
        bufN1, offE, slots_all, inc_v, nullptr, nullptr, bufM1, nullptr, bufM2, M);

    // efeat_new = relu(_ef3 @ W_e^T) -> d_out + N*D
    gemm_mfma<<<cdiv(M, 128), TB, 0, stream>>>(bufM2, W_e, D, 0, nullptr, efeat_new, M, 1);
}

// Round 5
// 576.543 us; speedup vs baseline: 10.4458x; 1.0936x over previous
//
#include <hip/hip_runtime.h>

#define D 128
#define SCAN_BLK 2048   // 256 threads * 8 elems

typedef __bf16 bf16;
typedef __attribute__((ext_vector_type(2))) __bf16 bf16x2;
typedef __attribute__((ext_vector_type(4))) __bf16 bf16x4;
typedef __attribute__((ext_vector_type(8))) __bf16 bf16x8;
typedef __attribute__((ext_vector_type(4))) float f32x4;

// ---------------- fp32 -> bf16 convert (float4/lane) -------------------------------------
__global__ __launch_bounds__(256) void cvt_bf16(
    const float* __restrict__ in, bf16* __restrict__ out, int n4)
{
    int i = blockIdx.x * 256 + threadIdx.x;
    if (i >= n4) return;
    float4 f = ((const float4*)in)[i];
    bf16x4 v = { (bf16)f.x, (bf16)f.y, (bf16)f.z, (bf16)f.w };
    ((bf16x4*)out)[i] = v;
}

// ---------------- MFMA GEMM: out[r,i] = act( X[r,:]@W[i,woff:woff+TK] + bscale[r]*bias[i] )
// X is R x TK bf16; W fp32 rows staged in LDS as bf16 with 16B-block XOR swizzle.
// 256 threads = 4 waves; wave computes 32 rows x 128 cols; block = 128 rows.
template<int TK>
__global__ __launch_bounds__(256) void gemm_mfma(
    const bf16* __restrict__ X, const float* __restrict__ W, int ldw, int woff,
    const float* __restrict__ bias, const float* __restrict__ bscale,
    float* __restrict__ outF, bf16* __restrict__ outH, int R, int doRelu)
{
    constexpr int BLKS = TK / 8;
    __shared__ __align__(16) bf16 Ws[D * TK];
    const int t = threadIdx.x;
    for (int g = t; g < D * BLKS; g += 256) {
        int row = g / BLKS, blk = g % BLKS;
        const float* src = W + (size_t)row * ldw + woff + blk * 8;
        float4 f0 = *(const float4*)(src);
        float4 f1 = *(const float4*)(src + 4);
        bf16x8 v = { (bf16)f0.x, (bf16)f0.y, (bf16)f0.z, (bf16)f0.w,
                     (bf16)f1.x, (bf16)f1.y, (bf16)f1.z, (bf16)f1.w };
        *(bf16x8*)(&Ws[row * TK + (blk ^ (row & 15)) * 8]) = v;
    }
    __syncthreads();

    const int lane = t & 63, wave = t >> 6;
    const int lrow = lane & 15, lk8 = lane >> 4;
    const int r0 = blockIdx.x * 128 + wave * 32;

    f32x4 acc[2][8] = {};
    for (int ks = 0; ks < TK / 32; ++ks) {
        bf16x8 a[2];
#pragma unroll
        for (int mf = 0; mf < 2; ++mf) {
            int r = r0 + mf * 16 + lrow;
            if (r > R - 1) r = R - 1;
            a[mf] = *(const bf16x8*)(X + (size_t)r * TK + ks * 32 + lk8 * 8);
        }
        bf16x8 b[8];
#pragma unroll
        for (int nf = 0; nf < 8; ++nf) {
            int row = nf * 16 + lrow;
            int blk = ks * 4 + lk8;
            b[nf] = *(const bf16x8*)(&Ws[row * TK + (blk ^ (row & 15)) * 8]);
        }
#pragma unroll
        for (int mf = 0; mf < 2; ++mf)
#pragma unroll
            for (int nf = 0; nf < 8; ++nf)
                acc[mf][nf] = __builtin_amdgcn_mfma_f32_16x16x32_bf16(a[mf], b[nf], acc[mf][nf], 0, 0, 0);
    }

#pragma unroll
    for (int mf = 0; mf < 2; ++mf) {
        int rbase = r0 + mf * 16 + (lane >> 4) * 4;
#pragma unroll
        for (int e = 0; e < 4; ++e) {
            int r = rbase + e;
            if (r >= R) continue;
            float bs = bias ? bscale[r] : 0.0f;
#pragma unroll
            for (int nf = 0; nf < 8; ++nf) {
                int col = nf * 16 + (lane & 15);
                float v = acc[mf][nf][e];
                if (bias) v += bs * bias[col];
                if (doRelu) v = fmaxf(v, 0.0f);
                if (outF) outF[(size_t)r * D + col] = v;
                if (outH) outH[(size_t)r * D + col] = (bf16)v;
            }
        }
    }
}

// ---------------- counting-sort building blocks ------------------------------------------
__global__ __launch_bounds__(256) void hist_kernel(
    const int* __restrict__ keys, int n, int* __restrict__ cnt)
{
    int i = blockIdx.x * 256 + threadIdx.x;
    if (i < n) atomicAdd(&cnt[keys[i]], 1);
}

__global__ __launch_bounds__(256) void scatter_kernel(
    const int* __restrict__ keys, int n, const int* __restrict__ off,
    int* __restrict__ cur, int* __restrict__ slots_all)
{
    int i = blockIdx.x * 256 + threadIdx.x;
    if (i >= n) return;
    int key = keys[i];
    int pos = off[key] + atomicAdd(&cur[key], 1);
    slots_all[pos] = i;
}

// ---------------- batched hierarchical exclusive scan ------------------------------------
__global__ __launch_bounds__(256) void scan_pass1(
    const int* __restrict__ in, int n, int* __restrict__ bsum)
{
    int b = blockIdx.x, t = threadIdx.x;
    int base = b * SCAN_BLK + t * 8;
    int s = 0;
#pragma unroll
    for (int j = 0; j < 8; ++j) { int i = base + j; if (i < n) s += in[i]; }
#pragma unroll
    for (int of = 1; of < 64; of <<= 1) s += __shfl_xor(s, of, 64);
    __shared__ int wsum[4];
    if ((t & 63) == 0) wsum[t >> 6] = s;
    __syncthreads();
    if (t == 0) bsum[b] = wsum[0] + wsum[1] + wsum[2] + wsum[3];
}

__global__ __launch_bounds__(256) void scan_pass2(int* __restrict__ bsum, int nb)
{
    __shared__ int carry, wsum[4], wpre[5];
    int t = threadIdx.x, wid = t >> 6, lane = t & 63;
    if (t == 0) carry = 0;
    __syncthreads();
    for (int base = 0; base < nb; base += 256) {
        int x = (base + t < nb) ? bsum[base + t] : 0;
        int v = x;
#pragma unroll
        for (int of = 1; of < 64; of <<= 1) {
            int u = __shfl_up(v, of, 64);
            if (lane >= of) v += u;
        }
        if (lane == 63) wsum[wid] = v;
        __syncthreads();
        if (t == 0) { int s = carry; for (int i = 0; i < 4; ++i) { wpre[i] = s; s += wsum[i]; } wpre[4] = s; }
        __syncthreads();
        if (base + t < nb) bsum[base + t] = wpre[wid] + v - x;
        __syncthreads();
        if (t == 0) carry = wpre[4];
        __syncthreads();
    }
}

__global__ __launch_bounds__(256) void scan_pass3(
    const int* __restrict__ in, int n, const int* __restrict__ bsum, int* __restrict__ out)
{
    int b = blockIdx.x, t = threadIdx.x, wid = t >> 6, lane = t & 63;
    int base = b * SCAN_BLK + t * 8;
    int x[8], s = 0;
#pragma unroll
    for (int j = 0; j < 8; ++j) { int i = base + j; x[j] = (i < n) ? in[i] : 0; s += x[j]; }
    int v = s;
#pragma unroll
    for (int of = 1; of < 64; of <<= 1) {
        int u = __shfl_up(v, of, 64);
        if (lane >= of) v += u;
    }
    __shared__ int wsum[4], wpre[4];
    if (lane == 63) wsum[wid] = v;
    __syncthreads();
    if (t == 0) { int acc = 0; for (int i = 0; i < 4; ++i) { wpre[i] = acc; acc += wsum[i]; } }
    __syncthreads();
    int pre = bsum[b] + wpre[wid] + (v - s);
#pragma unroll
    for (int j = 0; j < 8; ++j) { int i = base + j; if (i < n) out[i] = pre; pre += x[j]; }
}

// ---------------- CSR gather segment-reduce (bf16 sources, fp32 accum) -------------------
// KIND 0: spmm      w=sval[k];               out = acc (+ auxF row fp32)
// KIND 1: mean      w=gscale?gscale[gs]:1;   out = acc*rs
// KIND 3: mean+auxH                          out = acc*rs + auxH row (bf16)
// KIND 5: psi1      w=gscale[gs]; fac=sd*rs; out256 = [acc*rs ; efeatF*fac]; rowfac=fac
// KIND 6: psi2      w=1;          fac=cnt>0; out256 = [acc*rs ; efeatF*fac]; rowfac=fac
template<int KIND>
__global__ __launch_bounds__(256) void seg_gather(
    const bf16* __restrict__ src, const int* __restrict__ off, const int* __restrict__ slots,
    const int* __restrict__ gmap, const float* __restrict__ gscale, const float* __restrict__ sval,
    const float* __restrict__ auxF, const bf16* __restrict__ auxH,
    bf16* __restrict__ outH, float* __restrict__ rowfac, int R)
{
    int r = blockIdx.x * 4 + (threadIdx.x >> 6);
    if (r >= R) return;
    const int lane = threadIdx.x & 63;
    const int s0 = off[r], s1 = off[r + 1];
    float2 acc = {0.0f, 0.0f};
    float sd = 0.0f;
    for (int base = s0; base < s1; base += 64) {
        int nchunk = min(64, s1 - base);
        int mygs = 0;
        float myw = 1.0f;
        if (base + lane < s1) {
            int myk = slots[base + lane];
            mygs = gmap[myk];
            if (KIND == 0) myw = sval[myk];
            else if (KIND == 1 || KIND == 5) { if (gscale) myw = gscale[mygs]; }
        }
        for (int j = 0; j < nchunk; ++j) {
            int gs = __shfl(mygs, j, 64);
            float w = __shfl(myw, j, 64);
            bf16x2 v = *(const bf16x2*)(src + (size_t)gs * D + lane * 2);
            acc.x += (float)v.x * w;
            acc.y += (float)v.y * w;
            if (KIND == 5) sd += w;
        }
    }
    const int cnt = s1 - s0;
    const float rs = 1.0f / (float)max(cnt, 1);
    if (KIND == 0) {
        float2 o = acc;
        if (auxF) {
            float2 a = *(const float2*)(auxF + (size_t)r * D + lane * 2);
            o.x += a.x; o.y += a.y;
        }
        bf16x2 w = { (bf16)o.x, (bf16)o.y };
        *(bf16x2*)(outH + (size_t)r * D + lane * 2) = w;
    } else if (KIND == 1) {
        bf16x2 w = { (bf16)(acc.x * rs), (bf16)(acc.y * rs) };
        *(bf16x2*)(outH + (size_t)r * D + lane * 2) = w;
    } else if (KIND == 3) {
        bf16x2 a = *(const bf16x2*)(auxH + (size_t)r * D + lane * 2);
        bf16x2 w = { (bf16)(acc.x * rs + (float)a.x), (bf16)(acc.y * rs + (float)a.y) };
        *(bf16x2*)(outH + (size_t)r * D + lane * 2) = w;
    } else {  // 5 / 6
        float fac = (KIND == 5) ? sd * rs : (cnt > 0 ? 1.0f : 0.0f);
        bf16x2 w0 = { (bf16)(acc.x * rs), (bf16)(acc.y * rs) };
        *(bf16x2*)(outH + (size_t)r * 256 + lane * 2) = w0;
        float2 e = *(const float2*)(auxF + (size_t)r * D + lane * 2);
        bf16x2 w1 = { (bf16)(e.x * fac), (bf16)(e.y * fac) };
        *(bf16x2*)(outH + (size_t)r * 256 + 128 + lane * 2) = w1;
        if (lane == 0) rowfac[r] = fac;
    }
}

extern "C" void kernel_launch(void* const* d_in, const int* in_sizes, int n_in,
                              void* d_out, int out_size, void* d_ws, size_t ws_size,
                              hipStream_t stream) {
    const float* vfeat  = (const float*)d_in[0];
    const float* efeat  = (const float*)d_in[1];
    const float* invDV  = (const float*)d_in[2];
    const float* invDE  = (const float*)d_in[3];
    const int*   inc_v  = (const int*)d_in[4];
    const int*   inc_e  = (const int*)d_in[5];
    const int*   eM_row = (const int*)d_in[6];
    const int*   eM_col = (const int*)d_in[7];
    const float* eM_val = (const float*)d_in[8];
    const int*   vM_row = (const int*)d_in[9];
    const int*   vM_col = (const int*)d_in[10];
    const float* vM_val = (const float*)d_in[11];
    const float* W_psi1 = (const float*)d_in[12];
    const float* b_psi1 = (const float*)d_in[13];
    const float* W_psi2 = (const float*)d_in[14];
    const float* b_psi2 = (const float*)d_in[15];
    const float* W_v    = (const float*)d_in[16];
    const float* W_e    = (const float*)d_in[17];

    const int N = in_sizes[0] / D;
    const int M = in_sizes[1] / D;
    const int E = in_sizes[4];
    const int nnzE = in_sizes[6];
    const int nnzV = in_sizes[9];

    float* out = (float*)d_out;
    float* vfeat_new = out;                     // N*D
    float* efeat_new = out + (size_t)N * D;     // M*D

    // segment table: [cntE(M) gap][cntV(N) gap][cntEr(M) gap][cntVr(N) gap]
    const int T = 2 * M + 2 * N + 4;
    const int nbScan = (T + SCAN_BLK - 1) / SCAN_BLK;

    // workspace layout
    bf16* nA     = (bf16*)d_ws;                    // N*D  (vfeatH / _vfeatH / _vf2preH)
    bf16* nB     = nA + (size_t)N * D;             // N*D  (vnewH / _vf2H)
    bf16* psiIn  = nB + (size_t)N * D;             // M*256
    bf16* mE     = psiIn + (size_t)M * 256;        // M*D  (efeatH)
    bf16* mA     = mE + (size_t)M * D;             // M*D  (AH, then BH)
    bf16* mB     = mA + (size_t)M * D;             // M*D  (_efeatH, then _ef3H)
    float* rowfac = (float*)(mB + (size_t)M * D);  // M
    int* ip        = (int*)(rowfac + M);
    int* off_all   = ip;                 ip += T;
    int* cnt_all   = ip;                 ip += T;   // cnt_all & cur_all adjacent: one memset
    int* cur_all   = ip;                 ip += T;
    int* bsum      = ip;                 ip += nbScan + 1;
    int* slots_all = ip;                 // 2E + nnzE + nnzV ints

    int* offE  = off_all;
    int* offV  = offE + (M + 1);
    int* offEr = offV + (N + 1);
    int* offVr = offEr + (M + 1);
    const int bE  = 0;
    const int bV  = M + 1;
    const int bEr = bV + (N + 1);
    const int bVr = bEr + (M + 1);

    auto cdiv = [](int a, int b) { return (a + b - 1) / b; };
    const dim3 TB(256);

    // ---- build all 4 CSR orderings with ONE batched scan ----
    hipMemsetAsync(cnt_all, 0, (size_t)(2 * T) * 4, stream);
    hist_kernel<<<cdiv(E, 256), TB, 0, stream>>>(inc_e,  E,    cnt_all + bE);
    hist_kernel<<<cdiv(E, 256), TB, 0, stream>>>(inc_v,  E,    cnt_all + bV);
    hist_kernel<<<cdiv(nnzE, 256), TB, 0, stream>>>(eM_row, nnzE, cnt_all + bEr);
    hist_kernel<<<cdiv(nnzV, 256), TB, 0, stream>>>(vM_row, nnzV, cnt_all + bVr);
    scan_pass1<<<nbScan, TB, 0, stream>>>(cnt_all, T, bsum);
    scan_pass2<<<1, TB, 0, stream>>>(bsum, nbScan);
    scan_pass3<<<nbScan, TB, 0, stream>>>(cnt_all, T, bsum, off_all);
    scatter_kernel<<<cdiv(E, 256), TB, 0, stream>>>(inc_e,  E,    off_all + bE,  cur_all + bE,  slots_all);
    scatter_kernel<<<cdiv(E, 256), TB, 0, stream>>>(inc_v,  E,    off_all + bV,  cur_all + bV,  slots_all);
    scatter_kernel<<<cdiv(nnzE, 256), TB, 0, stream>>>(eM_row, nnzE, off_all + bEr, cur_all + bEr, slots_all);
    scatter_kernel<<<cdiv(nnzV, 256), TB, 0, stream>>>(vM_row, nnzV, off_all + bVr, cur_all + bVr, slots_all);

    // ---- bf16 copies of the two gathered inputs ----
    cvt_bf16<<<cdiv(N * D / 4, 256), TB, 0, stream>>>(vfeat, nA, N * D / 4);
    cvt_bf16<<<cdiv(M * D / 4, 256), TB, 0, stream>>>(efeat, mE, M * D / 4);

    // ---- pipeline ----
    // psiIn1 = [ (sum_v vfeatH*dv)/cnt ; efeat*(sd/cnt) ] ; rowfac = sd/cnt
    seg_gather<5><<<cdiv(M, 4), TB, 0, stream>>>(
        nA, offE, slots_all, inc_v, invDV, nullptr, efeat, nullptr, psiIn, rowfac, M);
    // A = psiIn1 @ W_psi1^T + rowfac*b1 -> AH (mA)
    gemm_mfma<256><<<cdiv(M, 128), TB, 0, stream>>>(
        psiIn, W_psi1, 2 * D, 0, b_psi1, rowfac, nullptr, mA, M, 0);
    // _efeat = spmm_E(A) + efeat -> mB
    seg_gather<0><<<cdiv(M, 4), TB, 0, stream>>>(
        mA, offEr, slots_all, eM_col, nullptr, eM_val, efeat, nullptr, mB, nullptr, M);
    // _vfeat = mean_v(_efeat[inc_e]) -> nA (vfeatH dead)
    seg_gather<1><<<cdiv(N, 4), TB, 0, stream>>>(
        mB, offV, slots_all, inc_e, nullptr, nullptr, nullptr, nullptr, nA, nullptr, N);
    // vfeat_new = relu(_vfeat @ W_v^T) -> d_out fp32 + nB bf16
    gemm_mfma<128><<<cdiv(N, 128), TB, 0, stream>>>(
        nA, W_v, D, 0, nullptr, nullptr, vfeat_new, nB, N, 1);
    // psiIn2 = [ mean_v(vnewH) ; efeat*[cnt>0] ] ; rowfac = [cnt>0]
    seg_gather<6><<<cdiv(M, 4), TB, 0, stream>>>(
        nB, offE, slots_all, inc_v, nullptr, nullptr, efeat, nullptr, psiIn, rowfac, M);
    // B = psiIn2 @ W_psi2^T + rowfac*b2 -> BH (mA; AH dead)
    gemm_mfma<256><<<cdiv(M, 128), TB, 0, stream>>>(
        psiIn, W_psi2, 2 * D, 0, b_psi2, rowfac, nullptr, mA, M, 0);
    // _vf2pre = mean_v(efeatH*invDE) -> nA
    seg_gather<1><<<cdiv(N, 4), TB, 0, stream>>>(
        mE, offV, slots_all, inc_e, invDE, nullptr, nullptr, nullptr, nA, nullptr, N);
    // _vf2 = spmm_V(_vf2pre) -> nB
    seg_gather<0><<<cdiv(N, 4), TB, 0, stream>>>(
        nA, offVr, slots_all, vM_col, nullptr, vM_val, nullptr, nullptr, nB, nullptr, N);
    // _ef3 = mean_e(_vf2[inc_v]) + B -> mB (_efeatH dead)
    seg_gather<3><<<cdiv(M, 4), TB, 0, stream>>>(
        nB, offE, slots_all, inc_v, nullptr, nullptr, nullptr, mA, mB, nullptr, M);
    // efeat_new = relu(_ef3 @ W_e^T) -> d_out + N*D
    gemm_mfma<128><<<cdiv(M, 128), TB, 0, stream>>>(
        mB, W_e, D, 0, nullptr, nullptr, efeat_new, nullptr, M, 1);
}

// Round 6
// 510.200 us; speedup vs baseline: 11.8041x; 1.1300x over previous
//
#include <hip/hip_runtime.h>

#define D 128
#define SCAN_BLK 2048   // 256 threads * 8 elems

typedef __bf16 bf16;
typedef __attribute__((ext_vector_type(4))) __bf16 bf16x4;
typedef __attribute__((ext_vector_type(8))) __bf16 bf16x8;
typedef __attribute__((ext_vector_type(4))) float f32x4;

// ---------------- fp32 -> bf16 convert (float4/lane) -------------------------------------
__global__ __launch_bounds__(256) void cvt_bf16(
    const float* __restrict__ in, bf16* __restrict__ out, int n4)
{
    int i = blockIdx.x * 256 + threadIdx.x;
    if (i >= n4) return;
    float4 f = ((const float4*)in)[i];
    bf16x4 v = { (bf16)f.x, (bf16)f.y, (bf16)f.z, (bf16)f.w };
    ((bf16x4*)out)[i] = v;
}

// ---------------- MFMA GEMM: out[r,i] = act( X@W^T + bscale[r]*bias[i] + addH[r,i] ) -----
template<int TK>
__global__ __launch_bounds__(256) void gemm_mfma(
    const bf16* __restrict__ X, const float* __restrict__ W, int ldw, int woff,
    const float* __restrict__ bias, const float* __restrict__ bscale,
    const bf16* __restrict__ addH,
    float* __restrict__ outF, bf16* __restrict__ outH, int R, int doRelu)
{
    constexpr int BLKS = TK / 8;
    __shared__ __align__(16) bf16 Ws[D * TK];
    const int t = threadIdx.x;
    for (int g = t; g < D * BLKS; g += 256) {
        int row = g / BLKS, blk = g % BLKS;
        const float* src = W + (size_t)row * ldw + woff + blk * 8;
        float4 f0 = *(const float4*)(src);
        float4 f1 = *(const float4*)(src + 4);
        bf16x8 v = { (bf16)f0.x, (bf16)f0.y, (bf16)f0.z, (bf16)f0.w,
                     (bf16)f1.x, (bf16)f1.y, (bf16)f1.z, (bf16)f1.w };
        *(bf16x8*)(&Ws[row * TK + (blk ^ (row & 15)) * 8]) = v;
    }
    __syncthreads();

    const int lane = t & 63, wave = t >> 6;
    const int lrow = lane & 15, lk8 = lane >> 4;
    const int r0 = blockIdx.x * 128 + wave * 32;

    f32x4 acc[2][8] = {};
    for (int ks = 0; ks < TK / 32; ++ks) {
        bf16x8 a[2];
#pragma unroll
        for (int mf = 0; mf < 2; ++mf) {
            int r = r0 + mf * 16 + lrow;
            if (r > R - 1) r = R - 1;
            a[mf] = *(const bf16x8*)(X + (size_t)r * TK + ks * 32 + lk8 * 8);
        }
        bf16x8 b[8];
#pragma unroll
        for (int nf = 0; nf < 8; ++nf) {
            int row = nf * 16 + lrow;
            int blk = ks * 4 + lk8;
            b[nf] = *(const bf16x8*)(&Ws[row * TK + (blk ^ (row & 15)) * 8]);
        }
#pragma unroll
        for (int mf = 0; mf < 2; ++mf)
#pragma unroll
            for (int nf = 0; nf < 8; ++nf)
                acc[mf][nf] = __builtin_amdgcn_mfma_f32_16x16x32_bf16(a[mf], b[nf], acc[mf][nf], 0, 0, 0);
    }

#pragma unroll
    for (int mf = 0; mf < 2; ++mf) {
        int rbase = r0 + mf * 16 + (lane >> 4) * 4;
#pragma unroll
        for (int e = 0; e < 4; ++e) {
            int r = rbase + e;
            if (r >= R) continue;
            float bs = bias ? bscale[r] : 0.0f;
#pragma unroll
            for (int nf = 0; nf < 8; ++nf) {
                int col = nf * 16 + (lane & 15);
                float v = acc[mf][nf][e];
                if (bias) v += bs * bias[col];
                if (addH) v += (float)addH[(size_t)r * D + col];
                if (doRelu) v = fmaxf(v, 0.0f);
                if (outF) outF[(size_t)r * D + col] = v;
                if (outH) outH[(size_t)r * D + col] = (bf16)v;
            }
        }
    }
}

// ---------------- counting-sort building blocks ------------------------------------------
__global__ __launch_bounds__(256) void hist_kernel(
    const int* __restrict__ keys, int n, int* __restrict__ cnt)
{
    int i = blockIdx.x * 256 + threadIdx.x;
    if (i < n) atomicAdd(&cnt[keys[i]], 1);
}

__global__ __launch_bounds__(256) void scatter_kernel(
    const int* __restrict__ keys, int n, const int* __restrict__ off,
    int* __restrict__ cur, int* __restrict__ slots_all)
{
    int i = blockIdx.x * 256 + threadIdx.x;
    if (i >= n) return;
    int key = keys[i];
    int pos = off[key] + atomicAdd(&cur[key], 1);
    slots_all[pos] = i;
}

// ---------------- batched hierarchical exclusive scan ------------------------------------
__global__ __launch_bounds__(256) void scan_pass1(
    const int* __restrict__ in, int n, int* __restrict__ bsum)
{
    int b = blockIdx.x, t = threadIdx.x;
    int base = b * SCAN_BLK + t * 8;
    int s = 0;
#pragma unroll
    for (int j = 0; j < 8; ++j) { int i = base + j; if (i < n) s += in[i]; }
#pragma unroll
    for (int of = 1; of < 64; of <<= 1) s += __shfl_xor(s, of, 64);
    __shared__ int wsum[4];
    if ((t & 63) == 0) wsum[t >> 6] = s;
    __syncthreads();
    if (t == 0) bsum[b] = wsum[0] + wsum[1] + wsum[2] + wsum[3];
}

__global__ __launch_bounds__(256) void scan_pass2(int* __restrict__ bsum, int nb)
{
    __shared__ int carry, wsum[4], wpre[5];
    int t = threadIdx.x, wid = t >> 6, lane = t & 63;
    if (t == 0) carry = 0;
    __syncthreads();
    for (int base = 0; base < nb; base += 256) {
        int x = (base + t < nb) ? bsum[base + t] : 0;
        int v = x;
#pragma unroll
        for (int of = 1; of < 64; of <<= 1) {
            int u = __shfl_up(v, of, 64);
            if (lane >= of) v += u;
        }
        if (lane == 63) wsum[wid] = v;
        __syncthreads();
        if (t == 0) { int s = carry; for (int i = 0; i < 4; ++i) { wpre[i] = s; s += wsum[i]; } wpre[4] = s; }
        __syncthreads();
        if (base + t < nb) bsum[base + t] = wpre[wid] + v - x;
        __syncthreads();
        if (t == 0) carry = wpre[4];
        __syncthreads();
    }
}

__global__ __launch_bounds__(256) void scan_pass3(
    const int* __restrict__ in, int n, const int* __restrict__ bsum, int* __restrict__ out)
{
    int b = blockIdx.x, t = threadIdx.x, wid = t >> 6, lane = t & 63;
    int base = b * SCAN_BLK + t * 8;
    int x[8], s = 0;
#pragma unroll
    for (int j = 0; j < 8; ++j) { int i = base + j; x[j] = (i < n) ? in[i] : 0; s += x[j]; }
    int v = s;
#pragma unroll
    for (int of = 1; of < 64; of <<= 1) {
        int u = __shfl_up(v, of, 64);
        if (lane >= of) v += u;
    }
    __shared__ int wsum[4], wpre[4];
    if (lane == 63) wsum[wid] = v;
    __syncthreads();
    if (t == 0) { int acc = 0; for (int i = 0; i < 4; ++i) { wpre[i] = acc; acc += wsum[i]; } }
    __syncthreads();
    int pre = bsum[b] + wpre[wid] + (v - s);
#pragma unroll
    for (int j = 0; j < 8; ++j) { int i = base + j; if (i < n) out[i] = pre; pre += x[j]; }
}

// ---------------- CSR gather segment-reduce (bf16 src, fp32 accum) -----------------------
// Wave per dest row; 4x 16-lane groups each process a different slot per iter (bf16x8/lane).
// KIND 0: spmm    w=sval[k];                out = acc (+auxF row)
// KIND 1: mean    w=gscale?gscale[gs]:1;    out = acc*rs
// KIND 6: psi2    w=1; fac=[cnt>0];         psiIn=[acc*rs ; auxF*fac]; rowfac=fac
// KIND 7: psi1+ef3pre  w=gscale[gs]; fac=sd*rs; psiIn=[acc*rs ; auxF*fac]; rowfac=fac;
//         acc2 = sum src2[gs] (unweighted); outH2 = acc2*rs
template<int KIND>
__global__ __launch_bounds__(256) void seg_gather(
    const bf16* __restrict__ src, const bf16* __restrict__ src2,
    const int* __restrict__ off, const int* __restrict__ slots,
    const int* __restrict__ gmap, const float* __restrict__ gscale,
    const float* __restrict__ sval, const float* __restrict__ auxF,
    bf16* __restrict__ outH, bf16* __restrict__ outH2,
    float* __restrict__ rowfac, int R)
{
    int r = blockIdx.x * 4 + (threadIdx.x >> 6);
    if (r >= R) return;
    const int lane = threadIdx.x & 63;
    const int q = lane >> 4, lc = lane & 15;
    const int s0 = off[r], s1 = off[r + 1];
    float acc[8] = {};
    float acc2[8] = {};
    float sd = 0.0f;
    for (int base = s0; base < s1; base += 64) {
        const int nchunk = min(64, s1 - base);
        int mygs = 0; float myw = 0.0f;
        if (base + lane < s1) {
            int myk = slots[base + lane];
            mygs = gmap[myk];
            if (KIND == 0) myw = sval[myk];
            else if (KIND == 1 || KIND == 7) myw = gscale ? gscale[mygs] : 1.0f;
            else myw = 1.0f;
        }
        for (int j = 0; j < nchunk; j += 4) {
            int g0 = __shfl(mygs, j, 64),     g1 = __shfl(mygs, j + 1, 64);
            int g2 = __shfl(mygs, j + 2, 64), g3 = __shfl(mygs, j + 3, 64);
            float w0 = __shfl(myw, j, 64),     w1 = __shfl(myw, j + 1, 64);
            float w2 = __shfl(myw, j + 2, 64), w3 = __shfl(myw, j + 3, 64);
            int gs  = q < 2 ? (q ? g1 : g0) : (q == 2 ? g2 : g3);
            float w = q < 2 ? (q ? w1 : w0) : (q == 2 ? w2 : w3);
            bf16x8 v = *(const bf16x8*)(src + (size_t)gs * D + lc * 8);
#pragma unroll
            for (int c = 0; c < 8; ++c) acc[c] += (float)v[c] * w;
            if (KIND == 7) {
                float wv = (j + q < nchunk) ? 1.0f : 0.0f;
                bf16x8 u = *(const bf16x8*)(src2 + (size_t)gs * D + lc * 8);
#pragma unroll
                for (int c = 0; c < 8; ++c) acc2[c] += (float)u[c] * wv;
                sd += w;
            }
        }
    }
#pragma unroll
    for (int c = 0; c < 8; ++c) {
        acc[c] += __shfl_xor(acc[c], 16, 64);
        acc[c] += __shfl_xor(acc[c], 32, 64);
    }
    if (KIND == 7) {
#pragma unroll
        for (int c = 0; c < 8; ++c) {
            acc2[c] += __shfl_xor(acc2[c], 16, 64);
            acc2[c] += __shfl_xor(acc2[c], 32, 64);
        }
        sd += __shfl_xor(sd, 16, 64);
        sd += __shfl_xor(sd, 32, 64);
    }
    const int cnt = s1 - s0;
    const float rs = 1.0f / (float)max(cnt, 1);

    if (KIND == 0) {
        if (q == 0) {
            float o[8];
#pragma unroll
            for (int c = 0; c < 8; ++c) o[c] = acc[c];
            if (auxF) {
                float4 a0 = *(const float4*)(auxF + (size_t)r * D + lc * 8);
                float4 a1 = *(const float4*)(auxF + (size_t)r * D + lc * 8 + 4);
                o[0] += a0.x; o[1] += a0.y; o[2] += a0.z; o[3] += a0.w;
                o[4] += a1.x; o[5] += a1.y; o[6] += a1.z; o[7] += a1.w;
            }
            bf16x8 wv;
#pragma unroll
            for (int c = 0; c < 8; ++c) wv[c] = (bf16)o[c];
            *(bf16x8*)(outH + (size_t)r * D + lc * 8) = wv;
        }
    } else if (KIND == 1) {
        if (q == 0) {
            bf16x8 wv;
#pragma unroll
            for (int c = 0; c < 8; ++c) wv[c] = (bf16)(acc[c] * rs);
            *(bf16x8*)(outH + (size_t)r * D + lc * 8) = wv;
        }
    } else {  // KIND 6 / 7
        float fac = (KIND == 7) ? sd * rs : (cnt > 0 ? 1.0f : 0.0f);
        if (q == 0) {
            bf16x8 wv;
#pragma unroll
            for (int c = 0; c < 8; ++c) wv[c] = (bf16)(acc[c] * rs);
            *(bf16x8*)(outH + (size_t)r * 256 + lc * 8) = wv;
            if (lane == 0) rowfac[r] = fac;
        } else if (q == 1 && KIND == 7) {
            bf16x8 wv;
#pragma unroll
            for (int c = 0; c < 8; ++c) wv[c] = (bf16)(acc2[c] * rs);
            *(bf16x8*)(outH2 + (size_t)r * D + lc * 8) = wv;
        } else if (q == 2) {
            float4 e0 = *(const float4*)(auxF + (size_t)r * D + lc * 8);
            float4 e1 = *(const float4*)(auxF + (size_t)r * D + lc * 8 + 4);
            bf16x8 wv = { (bf16)(e0.x * fac), (bf16)(e0.y * fac), (bf16)(e0.z * fac), (bf16)(e0.w * fac),
                          (bf16)(e1.x * fac), (bf16)(e1.y * fac), (bf16)(e1.z * fac), (bf16)(e1.w * fac) };
            *(bf16x8*)(outH + (size_t)r * 256 + 128 + lc * 8) = wv;
        }
    }
}

extern "C" void kernel_launch(void* const* d_in, const int* in_sizes, int n_in,
                              void* d_out, int out_size, void* d_ws, size_t ws_size,
                              hipStream_t stream) {
    const float* vfeat  = (const float*)d_in[0];
    const float* efeat  = (const float*)d_in[1];
    const float* invDV  = (const float*)d_in[2];
    const float* invDE  = (const float*)d_in[3];
    const int*   inc_v  = (const int*)d_in[4];
    const int*   inc_e  = (const int*)d_in[5];
    const int*   eM_row = (const int*)d_in[6];
    const int*   eM_col = (const int*)d_in[7];
    const float* eM_val = (const float*)d_in[8];
    const int*   vM_row = (const int*)d_in[9];
    const int*   vM_col = (const int*)d_in[10];
    const float* vM_val = (const float*)d_in[11];
    const float* W_psi1 = (const float*)d_in[12];
    const float* b_psi1 = (const float*)d_in[13];
    const float* W_psi2 = (const float*)d_in[14];
    const float* b_psi2 = (const float*)d_in[15];
    const float* W_v    = (const float*)d_in[16];
    const float* W_e    = (const float*)d_in[17];

    const int N = in_sizes[0] / D;
    const int M = in_sizes[1] / D;
    const int E = in_sizes[4];
    const int nnzE = in_sizes[6];
    const int nnzV = in_sizes[9];

    float* out = (float*)d_out;
    float* vfeat_new = out;                     // N*D
    float* efeat_new = out + (size_t)N * D;     // M*D

    const int T = 2 * M + 2 * N + 4;
    const int nbScan = (T + SCAN_BLK - 1) / SCAN_BLK;

    // workspace layout
    bf16* nA     = (bf16*)d_ws;                    // N*D  vfeatH -> _vfeatH
    bf16* nB     = nA + (size_t)N * D;             // N*D  _vf2preH
    bf16* nC     = nB + (size_t)N * D;             // N*D  _vf2H -> vnewH
    bf16* psiIn  = nC + (size_t)N * D;             // M*256
    bf16* mE     = psiIn + (size_t)M * 256;        // M*D  efeatH
    bf16* mA     = mE + (size_t)M * D;             // M*D  AH
    bf16* mB     = mA + (size_t)M * D;             // M*D  _efeatH -> _ef3H
    bf16* mC     = mB + (size_t)M * D;             // M*D  ef3preH
    float* rowfac = (float*)(mC + (size_t)M * D);  // M
    int* ip        = (int*)(rowfac + M);
    int* off_all   = ip;                 ip += T;
    int* cnt_all   = ip;                 ip += T;   // cnt_all & cur_all adjacent: one memset
    int* cur_all   = ip;                 ip += T;
    int* bsum      = ip;                 ip += nbScan + 1;
    int* slots_all = ip;                 // 2E + nnzE + nnzV ints

    int* offE  = off_all;
    int* offV  = offE + (M + 1);
    int* offEr = offV + (N + 1);
    int* offVr = offEr + (M + 1);
    const int bE  = 0;
    const int bV  = M + 1;
    const int bEr = bV + (N + 1);
    const int bVr = bEr + (M + 1);

    auto cdiv = [](int a, int b) { return (a + b - 1) / b; };
    const dim3 TB(256);

    // ---- build all 4 CSR orderings with ONE batched scan ----
    hipMemsetAsync(cnt_all, 0, (size_t)(2 * T) * 4, stream);
    hist_kernel<<<cdiv(E, 256), TB, 0, stream>>>(inc_e,  E,    cnt_all + bE);
    hist_kernel<<<cdiv(E, 256), TB, 0, stream>>>(inc_v,  E,    cnt_all + bV);
    hist_kernel<<<cdiv(nnzE, 256), TB, 0, stream>>>(eM_row, nnzE, cnt_all + bEr);
    hist_kernel<<<cdiv(nnzV, 256), TB, 0, stream>>>(vM_row, nnzV, cnt_all + bVr);
    scan_pass1<<<nbScan, TB, 0, stream>>>(cnt_all, T, bsum);
    scan_pass2<<<1, TB, 0, stream>>>(bsum, nbScan);
    scan_pass3<<<nbScan, TB, 0, stream>>>(cnt_all, T, bsum, off_all);
    scatter_kernel<<<cdiv(E, 256), TB, 0, stream>>>(inc_e,  E,    off_all + bE,  cur_all + bE,  slots_all);
    scatter_kernel<<<cdiv(E, 256), TB, 0, stream>>>(inc_v,  E,    off_all + bV,  cur_all + bV,  slots_all);
    scatter_kernel<<<cdiv(nnzE, 256), TB, 0, stream>>>(eM_row, nnzE, off_all + bEr, cur_all + bEr, slots_all);
    scatter_kernel<<<cdiv(nnzV, 256), TB, 0, stream>>>(vM_row, nnzV, off_all + bVr, cur_all + bVr, slots_all);

    // ---- bf16 copies of gathered inputs ----
    cvt_bf16<<<cdiv(N * D / 4, 256), TB, 0, stream>>>(vfeat, nA, N * D / 4);
    cvt_bf16<<<cdiv(M * D / 4, 256), TB, 0, stream>>>(efeat, mE, M * D / 4);

    // ---- pipeline (vf2 chain hoisted to front so ef3pre fuses into psi1 gather) ----
    // _vf2pre = mean_v(efeatH[inc_e]*invDE[inc_e]) -> nB
    seg_gather<1><<<cdiv(N, 4), TB, 0, stream>>>(
        mE, nullptr, offV, slots_all, inc_e, invDE, nullptr, nullptr, nB, nullptr, nullptr, N);
    // _vf2 = spmm_V(_vf2pre) -> nC
    seg_gather<0><<<cdiv(N, 4), TB, 0, stream>>>(
        nB, nullptr, offVr, slots_all, vM_col, nullptr, vM_val, nullptr, nC, nullptr, nullptr, N);
    // FUSED: psiIn1 = [mean_e(vfeatH*dv) ; efeat*fac], rowfac=fac=sd/cnt ; ef3pre=mean_e(_vf2) -> mC
    seg_gather<7><<<cdiv(M, 4), TB, 0, stream>>>(
        nA, nC, offE, slots_all, inc_v, invDV, nullptr, efeat, psiIn, mC, rowfac, M);
    // A = psiIn1 @ W_psi1^T + fac*b1 -> mA
    gemm_mfma<256><<<cdiv(M, 128), TB, 0, stream>>>(
        psiIn, W_psi1, 2 * D, 0, b_psi1, rowfac, nullptr, nullptr, mA, M, 0);
    // _efeat = spmm_E(A) + efeat -> mB
    seg_gather<0><<<cdiv(M, 4), TB, 0, stream>>>(
        mA, nullptr, offEr, slots_all, eM_col, nullptr, eM_val, efeat, mB, nullptr, nullptr, M);
    // _vfeat = mean_v(_efeat[inc_e]) -> nA (vfeatH dead)
    seg_gather<1><<<cdiv(N, 4), TB, 0, stream>>>(
        mB, nullptr, offV, slots_all, inc_e, nullptr, nullptr, nullptr, nA, nullptr, nullptr, N);
    // vfeat_new = relu(_vfeat @ W_v^T) -> d_out fp32 + nC bf16 (vf2H dead)
    gemm_mfma<128><<<cdiv(N, 128), TB, 0, stream>>>(
        nA, W_v, D, 0, nullptr, nullptr, nullptr, vfeat_new, nC, N, 1);
    // psiIn2 = [mean_e(vnewH) ; efeat*[cnt>0]] ; rowfac
    seg_gather<6><<<cdiv(M, 4), TB, 0, stream>>>(
        nC, nullptr, offE, slots_all, inc_v, nullptr, nullptr, efeat, psiIn, nullptr, rowfac, M);
    // _ef3 = psiIn2 @ W_psi2^T + fac*b2 + ef3pre -> mB
    gemm_mfma<256><<<cdiv(M, 128), TB, 0, stream>>>(
        psiIn, W_psi2, 2 * D, 0, b_psi2, rowfac, mC, nullptr, mB, M, 0);
    // efeat_new = relu(_ef3 @ W_e^T) -> d_out + N*D
    gemm_mfma<128><<<cdiv(M, 128), TB, 0, stream>>>(
        mB, W_e, D, 0, nullptr, nullptr, nullptr, efeat_new, nullptr, M, 1);
}

// Round 7
// 453.036 us; speedup vs baseline: 13.2935x; 1.1262x over previous
//
#include <hip/hip_runtime.h>

#define D 128
#define SCAN_BLK 2048   // 256 threads * 8 elems

typedef __bf16 bf16;
typedef __attribute__((ext_vector_type(4))) __bf16 bf16x4;
typedef __attribute__((ext_vector_type(8))) __bf16 bf16x8;
typedef __attribute__((ext_vector_type(4))) float f32x4;

// ---------------- fp32 -> bf16 convert (float4/lane) -------------------------------------
__global__ __launch_bounds__(256) void cvt_bf16(
    const float* __restrict__ in, bf16* __restrict__ out, int n4)
{
    int i = blockIdx.x * 256 + threadIdx.x;
    if (i >= n4) return;
    float4 f = ((const float4*)in)[i];
    bf16x4 v = { (bf16)f.x, (bf16)f.y, (bf16)f.z, (bf16)f.w };
    ((bf16x4*)out)[i] = v;
}

// ---------------- weight folding: W1f = Wv@W_psi1 (128x256), b1f = Wv@b1; same for We/W2 --
__global__ __launch_bounds__(256) void wfold(
    const float* __restrict__ Wv, const float* __restrict__ W1, const float* __restrict__ b1,
    const float* __restrict__ We, const float* __restrict__ W2, const float* __restrict__ b2,
    float* __restrict__ W1f, float* __restrict__ b1f,
    float* __restrict__ W2f, float* __restrict__ b2f)
{
    int gid = blockIdx.x * 256 + threadIdx.x;
    if (gid < 65536) {
        int which = gid >> 15;
        int i = (gid >> 8) & 127;
        int j = gid & 255;
        const float* A = which ? We : Wv;
        const float* B = which ? W2 : W1;
        float s = 0.0f;
        for (int k = 0; k < 128; ++k) s += A[i * 128 + k] * B[k * 256 + j];
        (which ? W2f : W1f)[i * 256 + j] = s;
    } else if (gid < 65536 + 256) {
        int t = gid - 65536, which = t >> 7, i = t & 127;
        const float* A = which ? We : Wv;
        const float* B = which ? b2 : b1;
        float s = 0.0f;
        for (int k = 0; k < 128; ++k) s += A[i * 128 + k] * B[k];
        (which ? b2f : b1f)[i] = s;
    }
}

// ---------------- MFMA GEMM (K=128): outH[r,i] = X[r,:]@W[i,:]  ---------------------------
__global__ __launch_bounds__(256) void gemm_mfma(
    const bf16* __restrict__ X, const float* __restrict__ W, int ldw,
    bf16* __restrict__ outH, int R)
{
    __shared__ __align__(16) bf16 Ws[D * D];
    const int t = threadIdx.x;
    for (int g = t; g < D * 16; g += 256) {
        int row = g >> 4, blk = g & 15;
        const float* src = W + (size_t)row * ldw + blk * 8;
        float4 f0 = *(const float4*)(src);
        float4 f1 = *(const float4*)(src + 4);
        bf16x8 v = { (bf16)f0.x, (bf16)f0.y, (bf16)f0.z, (bf16)f0.w,
                     (bf16)f1.x, (bf16)f1.y, (bf16)f1.z, (bf16)f1.w };
        *(bf16x8*)(&Ws[row * D + (blk ^ (row & 15)) * 8]) = v;
    }
    __syncthreads();

    const int lane = t & 63, wave = t >> 6;
    const int lrow = lane & 15, lk8 = lane >> 4;
    const int r0 = blockIdx.x * 128 + wave * 32;

    f32x4 acc[2][8] = {};
    for (int ks = 0; ks < 4; ++ks) {
        bf16x8 a[2];
#pragma unroll
        for (int mf = 0; mf < 2; ++mf) {
            int r = r0 + mf * 16 + lrow;
            if (r > R - 1) r = R - 1;
            a[mf] = *(const bf16x8*)(X + (size_t)r * D + ks * 32 + lk8 * 8);
        }
        bf16x8 b[8];
#pragma unroll
        for (int nf = 0; nf < 8; ++nf) {
            int row = nf * 16 + lrow;
            int blk = ks * 4 + lk8;
            b[nf] = *(const bf16x8*)(&Ws[row * D + (blk ^ (row & 15)) * 8]);
        }
#pragma unroll
        for (int mf = 0; mf < 2; ++mf)
#pragma unroll
            for (int nf = 0; nf < 8; ++nf)
                acc[mf][nf] = __builtin_amdgcn_mfma_f32_16x16x32_bf16(a[mf], b[nf], acc[mf][nf], 0, 0, 0);
    }

#pragma unroll
    for (int mf = 0; mf < 2; ++mf) {
        int rbase = r0 + mf * 16 + (lane >> 4) * 4;
#pragma unroll
        for (int e = 0; e < 4; ++e) {
            int r = rbase + e;
            if (r >= R) continue;
#pragma unroll
            for (int nf = 0; nf < 8; ++nf)
                outH[(size_t)r * D + nf * 16 + (lane & 15)] = (bf16)acc[mf][nf][e];
        }
    }
}

// ---------------- PSI MFMA GEMM (K=256): out = act([X1 ; X2*fac] @ Wf^T + fac*bf + addH) --
__global__ __launch_bounds__(256) void gemm_psi(
    const bf16* __restrict__ X1, const bf16* __restrict__ X2,
    const float* __restrict__ rowfac, const float* __restrict__ Wf,
    const float* __restrict__ bf_, const bf16* __restrict__ addH,
    float* __restrict__ outF, bf16* __restrict__ outH, int R, int doRelu)
{
    __shared__ __align__(16) bf16 Ws[D * 256];   // 64 KB
    const int t = threadIdx.x;
    for (int g = t; g < D * 32; g += 256) {
        int row = g >> 5, blk = g & 31;
        const float* src = Wf + (size_t)row * 256 + blk * 8;
        float4 f0 = *(const float4*)(src);
        float4 f1 = *(const float4*)(src + 4);
        bf16x8 v = { (bf16)f0.x, (bf16)f0.y, (bf16)f0.z, (bf16)f0.w,
                     (bf16)f1.x, (bf16)f1.y, (bf16)f1.z, (bf16)f1.w };
        *(bf16x8*)(&Ws[row * 256 + (blk ^ (row & 15)) * 8]) = v;
    }
    __syncthreads();

    const int lane = t & 63, wave = t >> 6;
    const int lrow = lane & 15, lk8 = lane >> 4;
    const int r0 = blockIdx.x * 128 + wave * 32;

    int rr[2]; float fac[2];
#pragma unroll
    for (int mf = 0; mf < 2; ++mf) {
        rr[mf] = min(r0 + mf * 16 + lrow, R - 1);
        fac[mf] = rowfac[rr[mf]];
    }

    f32x4 acc[2][8] = {};
    for (int ks = 0; ks < 8; ++ks) {
        bf16x8 a[2];
#pragma unroll
        for (int mf = 0; mf < 2; ++mf) {
            if (ks < 4) {
                a[mf] = *(const bf16x8*)(X1 + (size_t)rr[mf] * D + ks * 32 + lk8 * 8);
            } else {
                bf16x8 m = *(const bf16x8*)(X2 + (size_t)rr[mf] * D + (ks - 4) * 32 + lk8 * 8);
#pragma unroll
                for (int c = 0; c < 8; ++c) a[mf][c] = (bf16)((float)m[c] * fac[mf]);
            }
        }
        bf16x8 b[8];
#pragma unroll
        for (int nf = 0; nf < 8; ++nf) {
            int row = nf * 16 + lrow;
            int blk = ks * 4 + lk8;
            b[nf] = *(const bf16x8*)(&Ws[row * 256 + (blk ^ (row & 15)) * 8]);
        }
#pragma unroll
        for (int mf = 0; mf < 2; ++mf)
#pragma unroll
            for (int nf = 0; nf < 8; ++nf)
                acc[mf][nf] = __builtin_amdgcn_mfma_f32_16x16x32_bf16(a[mf], b[nf], acc[mf][nf], 0, 0, 0);
    }

#pragma unroll
    for (int mf = 0; mf < 2; ++mf) {
        int rbase = r0 + mf * 16 + (lane >> 4) * 4;
#pragma unroll
        for (int e = 0; e < 4; ++e) {
            int r = rbase + e;
            if (r >= R) continue;
            float bs = rowfac[r];
#pragma unroll
            for (int nf = 0; nf < 8; ++nf) {
                int col = nf * 16 + (lane & 15);
                float v = acc[mf][nf][e] + bs * bf_[col];
                if (addH) v += (float)addH[(size_t)r * D + col];
                if (doRelu) v = fmaxf(v, 0.0f);
                if (outF) outF[(size_t)r * D + col] = v;
                if (outH) outH[(size_t)r * D + col] = (bf16)v;
            }
        }
    }
}

// ---------------- merged histogram over all 4 key arrays ---------------------------------
__global__ __launch_bounds__(256) void hist_all(
    const int* __restrict__ ie, const int* __restrict__ iv,
    const int* __restrict__ er, const int* __restrict__ vr,
    int E, int nnzE, int nnzV, int bV, int bEr, int bVr, int* __restrict__ cnt)
{
    int gid = blockIdx.x * 256 + threadIdx.x;
    if (gid < E) atomicAdd(cnt + ie[gid], 1);
    else if (gid < 2 * E) atomicAdd(cnt + bV + iv[gid - E], 1);
    else if (gid < 2 * E + nnzE) atomicAdd(cnt + bEr + er[gid - 2 * E], 1);
    else if (gid < 2 * E + nnzE + nnzV) atomicAdd(cnt + bVr + vr[gid - 2 * E - nnzE], 1);
}

// ---------------- merged scatter: writes composed gs (and weight for nnz regions) --------
__global__ __launch_bounds__(256) void scatter_all(
    const int* __restrict__ ie, const int* __restrict__ iv,
    const int* __restrict__ er_r, const int* __restrict__ er_c, const float* __restrict__ er_v,
    const int* __restrict__ vr_r, const int* __restrict__ vr_c, const float* __restrict__ vr_v,
    int E, int nnzE, int nnzV, int bV, int bEr, int bVr,
    const int* __restrict__ off, int* __restrict__ cur,
    int* __restrict__ gs_all, float* __restrict__ w_sh)
{
    int gid = blockIdx.x * 256 + threadIdx.x;
    int key, gs, obase; float w = 0.0f; bool hasw = false;
    if (gid < E) { key = ie[gid]; gs = iv[gid]; obase = 0; }
    else if (gid < 2 * E) { int i = gid - E; key = iv[i]; gs = ie[i]; obase = bV; }
    else if (gid < 2 * E + nnzE) { int i = gid - 2 * E; key = er_r[i]; gs = er_c[i]; w = er_v[i]; hasw = true; obase = bEr; }
    else if (gid < 2 * E + nnzE + nnzV) { int i = gid - 2 * E - nnzE; key = vr_r[i]; gs = vr_c[i]; w = vr_v[i]; hasw = true; obase = bVr; }
    else return;
    int pos = off[obase + key] + atomicAdd(cur + obase + key, 1);
    gs_all[pos] = gs;
    if (hasw) w_sh[pos] = w;
}

// ---------------- batched hierarchical exclusive scan ------------------------------------
__global__ __launch_bounds__(256) void scan_pass1(
    const int* __restrict__ in, int n, int* __restrict__ bsum)
{
    int b = blockIdx.x, t = threadIdx.x;
    int base = b * SCAN_BLK + t * 8;
    int s = 0;
#pragma unroll
    for (int j = 0; j < 8; ++j) { int i = base + j; if (i < n) s += in[i]; }
#pragma unroll
    for (int of = 1; of < 64; of <<= 1) s += __shfl_xor(s, of, 64);
    __shared__ int wsum[4];
    if ((t & 63) == 0) wsum[t >> 6] = s;
    __syncthreads();
    if (t == 0) bsum[b] = wsum[0] + wsum[1] + wsum[2] + wsum[3];
}

__global__ __launch_bounds__(256) void scan_pass2(int* __restrict__ bsum, int nb)
{
    __shared__ int carry, wsum[4], wpre[5];
    int t = threadIdx.x, wid = t >> 6, lane = t & 63;
    if (t == 0) carry = 0;
    __syncthreads();
    for (int base = 0; base < nb; base += 256) {
        int x = (base + t < nb) ? bsum[base + t] : 0;
        int v = x;
#pragma unroll
        for (int of = 1; of < 64; of <<= 1) {
            int u = __shfl_up(v, of, 64);
            if (lane >= of) v += u;
        }
        if (lane == 63) wsum[wid] = v;
        __syncthreads();
        if (t == 0) { int s = carry; for (int i = 0; i < 4; ++i) { wpre[i] = s; s += wsum[i]; } wpre[4] = s; }
        __syncthreads();
        if (base + t < nb) bsum[base + t] = wpre[wid] + v - x;
        __syncthreads();
        if (t == 0) carry = wpre[4];
        __syncthreads();
    }
}

__global__ __launch_bounds__(256) void scan_pass3(
    const int* __restrict__ in, int n, const int* __restrict__ bsum, int* __restrict__ out)
{
    int b = blockIdx.x, t = threadIdx.x, wid = t >> 6, lane = t & 63;
    int base = b * SCAN_BLK + t * 8;
    int x[8], s = 0;
#pragma unroll
    for (int j = 0; j < 8; ++j) { int i = base + j; x[j] = (i < n) ? in[i] : 0; s += x[j]; }
    int v = s;
#pragma unroll
    for (int of = 1; of < 64; of <<= 1) {
        int u = __shfl_up(v, of, 64);
        if (lane >= of) v += u;
    }
    __shared__ int wsum[4], wpre[4];
    if (lane == 63) wsum[wid] = v;
    __syncthreads();
    if (t == 0) { int acc = 0; for (int i = 0; i < 4; ++i) { wpre[i] = acc; acc += wsum[i]; } }
    __syncthreads();
    int pre = bsum[b] + wpre[wid] + (v - s);
#pragma unroll
    for (int j = 0; j < 8; ++j) { int i = base + j; if (i < n) out[i] = pre; pre += x[j]; }
}

// ---------------- CSR gather segment-reduce (bf16 src, fp32 accum, de-indirected) --------
// Wave per dest row; 4x 16-lane groups each process a different slot per iter (bf16x8/lane).
// KIND 0: spmm   w=w_sh[slot];  out = acc (+auxH row)
// KIND 1: mean   w=gscale[gs];  out = acc*rs
// KIND 2: mean   w=1;           outH = bf16(relu(acc*rs)), outF = fp32(relu(acc*rs))
// KIND 6: mean   w=1;           out = acc*rs; rowfac=[cnt>0]
// KIND 7: mean   w=gscale[gs];  out = acc*rs; outH2 = (unweighted mean of src2); rowfac=sd*rs
template<int KIND>
__global__ __launch_bounds__(256) void seg_gather(
    const bf16* __restrict__ src, const bf16* __restrict__ src2,
    const int* __restrict__ off, const int* __restrict__ gs_all,
    const float* __restrict__ w_sh, const float* __restrict__ gscale,
    const bf16* __restrict__ auxH,
    bf16* __restrict__ outH, bf16* __restrict__ outH2,
    float* __restrict__ outF, float* __restrict__ rowfac, int R)
{
    int r = blockIdx.x * 4 + (threadIdx.x >> 6);
    if (r >= R) return;
    const int lane = threadIdx.x & 63;
    const int q = lane >> 4, lc = lane & 15;
    const int s0 = off[r], s1 = off[r + 1];
    float acc[8] = {}, acc2[8] = {};
    float sd = 0.0f;
    for (int base = s0; base < s1; base += 64) {
        const int nchunk = min(64, s1 - base);
        int mygs = 0; float myw = 0.0f;
        if (base + lane < s1) {
            mygs = gs_all[base + lane];
            if (KIND == 0) myw = w_sh[base + lane];
            else if (KIND == 1 || KIND == 7) myw = gscale[mygs];
            else myw = 1.0f;
        }
        for (int j = 0; j < nchunk; j += 4) {
            int g0 = __shfl(mygs, j, 64),     g1 = __shfl(mygs, j + 1, 64);
            int g2 = __shfl(mygs, j + 2, 64), g3 = __shfl(mygs, j + 3, 64);
            float w0 = __shfl(myw, j, 64),     w1 = __shfl(myw, j + 1, 64);
            float w2 = __shfl(myw, j + 2, 64), w3 = __shfl(myw, j + 3, 64);
            int gs  = q < 2 ? (q ? g1 : g0) : (q == 2 ? g2 : g3);
            float w = q < 2 ? (q ? w1 : w0) : (q == 2 ? w2 : w3);
            bf16x8 v = *(const bf16x8*)(src + (size_t)gs * D + lc * 8);
#pragma unroll
            for (int c = 0; c < 8; ++c) acc[c] += (float)v[c] * w;
            if (KIND == 7) {
                float wv = (j + q < nchunk) ? 1.0f : 0.0f;
                bf16x8 u = *(const bf16x8*)(src2 + (size_t)gs * D + lc * 8);
#pragma unroll
                for (int c = 0; c < 8; ++c) acc2[c] += (float)u[c] * wv;
                sd += w;
            }
        }
    }
#pragma unroll
    for (int c = 0; c < 8; ++c) {
        acc[c] += __shfl_xor(acc[c], 16, 64);
        acc[c] += __shfl_xor(acc[c], 32, 64);
    }
    if (KIND == 7) {
#pragma unroll
        for (int c = 0; c < 8; ++c) {
            acc2[c] += __shfl_xor(acc2[c], 16, 64);
            acc2[c] += __shfl_xor(acc2[c], 32, 64);
        }
        sd += __shfl_xor(sd, 16, 64);
        sd += __shfl_xor(sd, 32, 64);
    }
    const int cnt = s1 - s0;
    const float rs = 1.0f / (float)max(cnt, 1);

    if (KIND == 0) {
        if (q == 0) {
            float o[8];
#pragma unroll
            for (int c = 0; c < 8; ++c) o[c] = acc[c];
            if (auxH) {
                bf16x8 a = *(const bf16x8*)(auxH + (size_t)r * D + lc * 8);
#pragma unroll
                for (int c = 0; c < 8; ++c) o[c] += (float)a[c];
            }
            bf16x8 wv;
#pragma unroll
            for (int c = 0; c < 8; ++c) wv[c] = (bf16)o[c];
            *(bf16x8*)(outH + (size_t)r * D + lc * 8) = wv;
        }
    } else if (KIND == 1 || KIND == 6) {
        if (q == 0) {
            bf16x8 wv;
#pragma unroll
            for (int c = 0; c < 8; ++c) wv[c] = (bf16)(acc[c] * rs);
            *(bf16x8*)(outH + (size_t)r * D + lc * 8) = wv;
        }
        if (KIND == 6 && lane == 0) rowfac[r] = (cnt > 0) ? 1.0f : 0.0f;
    } else if (KIND == 2) {
        if (q == 0) {
            bf16x8 wv;
#pragma unroll
            for (int c = 0; c < 8; ++c) wv[c] = (bf16)fmaxf(acc[c] * rs, 0.0f);
            *(bf16x8*)(outH + (size_t)r * D + lc * 8) = wv;
        } else if (q == 1) {
            float4 o0 = { fmaxf(acc[0] * rs, 0.0f), fmaxf(acc[1] * rs, 0.0f),
                          fmaxf(acc[2] * rs, 0.0f), fmaxf(acc[3] * rs, 0.0f) };
            float4 o1 = { fmaxf(acc[4] * rs, 0.0f), fmaxf(acc[5] * rs, 0.0f),
                          fmaxf(acc[6] * rs, 0.0f), fmaxf(acc[7] * rs, 0.0f) };
            *(float4*)(outF + (size_t)r * D + lc * 8) = o0;
            *(float4*)(outF + (size_t)r * D + lc * 8 + 4) = o1;
        }
    } else {  // KIND 7
        if (q == 0) {
            bf16x8 wv;
#pragma unroll
            for (int c = 0; c < 8; ++c) wv[c] = (bf16)(acc[c] * rs);
            *(bf16x8*)(outH + (size_t)r * D + lc * 8) = wv;
        } else if (q == 1) {
            bf16x8 wv;
#pragma unroll
            for (int c = 0; c < 8; ++c) wv[c] = (bf16)(acc2[c] * rs);
            *(bf16x8*)(outH2 + (size_t)r * D + lc * 8) = wv;
        }
        if (lane == 0) rowfac[r] = sd * rs;
    }
}

extern "C" void kernel_launch(void* const* d_in, const int* in_sizes, int n_in,
                              void* d_out, int out_size, void* d_ws, size_t ws_size,
                              hipStream_t stream) {
    const float* vfeat  = (const float*)d_in[0];
    const float* efeat  = (const float*)d_in[1];
    const float* invDV  = (const float*)d_in[2];
    const float* invDE  = (const float*)d_in[3];
    const int*   inc_v  = (const int*)d_in[4];
    const int*   inc_e  = (const int*)d_in[5];
    const int*   eM_row = (const int*)d_in[6];
    const int*   eM_col = (const int*)d_in[7];
    const float* eM_val = (const float*)d_in[8];
    const int*   vM_row = (const int*)d_in[9];
    const int*   vM_col = (const int*)d_in[10];
    const float* vM_val = (const float*)d_in[11];
    const float* W_psi1 = (const float*)d_in[12];
    const float* b_psi1 = (const float*)d_in[13];
    const float* W_psi2 = (const float*)d_in[14];
    const float* b_psi2 = (const float*)d_in[15];
    const float* W_v    = (const float*)d_in[16];
    const float* W_e    = (const float*)d_in[17];

    const int N = in_sizes[0] / D;
    const int M = in_sizes[1] / D;
    const int E = in_sizes[4];
    const int nnzE = in_sizes[6];
    const int nnzV = in_sizes[9];
    const int TH = 2 * E + nnzE + nnzV;

    float* out = (float*)d_out;
    float* vfeat_new = out;                     // N*D
    float* efeat_new = out + (size_t)N * D;     // M*D

    const int T = 2 * M + 2 * N + 4;
    const int nbScan = (T + SCAN_BLK - 1) / SCAN_BLK;

    // workspace layout (bf16 first, 16B-aligned sections)
    bf16* nA  = (bf16*)d_ws;                    // N*D  vfeatH
    bf16* nB  = nA + (size_t)N * D;             // N*D  vf2preW
    bf16* nC  = nB + (size_t)N * D;             // N*D  vf2W -> vnewH
    bf16* mE  = nC + (size_t)N * D;             // M*D  efeatH
    bf16* mWe = mE + (size_t)M * D;             // M*D  efW_e -> A' (mA)
    bf16* mV  = mWe + (size_t)M * D;            // M*D  efW_v
    bf16* mB  = mV + (size_t)M * D;             // M*D  _efeatV
    bf16* mC  = mB + (size_t)M * D;             // M*D  ef3preW
    bf16* mP  = mC + (size_t)M * D;             // M*D  psi gather out (1 then 2)
    bf16* mA  = mWe;                            // alias: A' after efW_e dead
    float* W1f = (float*)(mP + (size_t)M * D);  // 128*256
    float* W2f = W1f + 128 * 256;               // 128*256
    float* b1f = W2f + 128 * 256;               // 128
    float* b2f = b1f + 128;                     // 128
    float* rowfac = b2f + 128;                  // M
    int* cnt_all = (int*)(rowfac + M);          // T (scanned in-place -> off_all)
    int* cur_all = cnt_all + T;                 // T
    int* bsum    = cur_all + T;                 // nbScan+1
    int* gs_all  = bsum + nbScan + 1;           // TH
    float* w_all = (float*)(gs_all + TH);       // nnzE+nnzV
    float* w_sh  = w_all - (size_t)2 * E;       // indexed by global slot >= 2E

    int* off_all = cnt_all;
    const int bV  = M + 1;
    const int bEr = bV + (N + 1);
    const int bVr = bEr + (M + 1);
    int* offE  = off_all;
    int* offV  = off_all + bV;
    int* offEr = off_all + bEr;
    int* offVr = off_all + bVr;

    auto cdiv = [](int a, int b) { return (a + b - 1) / b; };
    const dim3 TB(256);

    // ---- CSR build: one memset, merged hist, batched scan (in place), merged scatter ----
    hipMemsetAsync(cnt_all, 0, (size_t)(2 * T) * 4, stream);
    hist_all<<<cdiv(TH, 256), TB, 0, stream>>>(inc_e, inc_v, eM_row, vM_row,
                                               E, nnzE, nnzV, bV, bEr, bVr, cnt_all);
    scan_pass1<<<nbScan, TB, 0, stream>>>(cnt_all, T, bsum);
    scan_pass2<<<1, TB, 0, stream>>>(bsum, nbScan);
    scan_pass3<<<nbScan, TB, 0, stream>>>(cnt_all, T, bsum, off_all);
    scatter_all<<<cdiv(TH, 256), TB, 0, stream>>>(
        inc_e, inc_v, eM_row, eM_col, eM_val, vM_row, vM_col, vM_val,
        E, nnzE, nnzV, bV, bEr, bVr, off_all, cur_all, gs_all, w_sh);

    // ---- bf16 inputs + folded weights ----
    cvt_bf16<<<cdiv(N * D / 4, 256), TB, 0, stream>>>(vfeat, nA, N * D / 4);
    cvt_bf16<<<cdiv(M * D / 4, 256), TB, 0, stream>>>(efeat, mE, M * D / 4);
    wfold<<<257, TB, 0, stream>>>(W_v, W_psi1, b_psi1, W_e, W_psi2, b_psi2,
                                  W1f, b1f, W2f, b2f);

    // ---- pipeline (fully in Wv/We-transformed space for the two chains) ----
    // efW_e = efeat @ W_e^T ; efW_v = efeat @ W_v^T
    gemm_mfma<<<cdiv(M, 128), TB, 0, stream>>>(mE, W_e, D, mWe, M);
    gemm_mfma<<<cdiv(M, 128), TB, 0, stream>>>(mE, W_v, D, mV, M);
    // vf2preW = mean_v(efW_e[inc_e] * invDE[inc_e]) -> nB
    seg_gather<1><<<cdiv(N, 4), TB, 0, stream>>>(
        mWe, nullptr, offV, gs_all, nullptr, invDE, nullptr, nB, nullptr, nullptr, nullptr, N);
    // vf2W = spmm_V(vf2preW) -> nC
    seg_gather<0><<<cdiv(N, 4), TB, 0, stream>>>(
        nB, nullptr, offVr, gs_all, w_sh, nullptr, nullptr, nC, nullptr, nullptr, nullptr, N);
    // FUSED psi1: mP = mean_w(vfeatH*dv); mC = ef3preW = mean(vf2W); rowfac = sd/cnt
    seg_gather<7><<<cdiv(M, 4), TB, 0, stream>>>(
        nA, nC, offE, gs_all, nullptr, invDV, nullptr, mP, mC, nullptr, rowfac, M);
    // A' = [mP ; mE*fac] @ W1f^T + fac*b1f -> mA (bf16)
    gemm_psi<<<cdiv(M, 128), TB, 0, stream>>>(
        mP, mE, rowfac, W1f, b1f, nullptr, nullptr, mA, M, 0);
    // _efeatV = spmm_E(A') + efW_v -> mB
    seg_gather<0><<<cdiv(M, 4), TB, 0, stream>>>(
        mA, nullptr, offEr, gs_all, w_sh, nullptr, mV, mB, nullptr, nullptr, nullptr, M);
    // vfeat_new = relu(mean_v(_efeatV)) -> d_out fp32 + nC bf16 (vf2W dead)
    seg_gather<2><<<cdiv(N, 4), TB, 0, stream>>>(
        mB, nullptr, offV, gs_all, nullptr, nullptr, nullptr, nC, nullptr, vfeat_new, nullptr, N);
    // psi2: mP = mean(vnewH); rowfac = [cnt>0]
    seg_gather<6><<<cdiv(M, 4), TB, 0, stream>>>(
        nC, nullptr, offE, gs_all, nullptr, nullptr, nullptr, mP, nullptr, nullptr, rowfac, M);
    // efeat_new = relu([mP ; mE*fac] @ W2f^T + fac*b2f + ef3preW) -> d_out
    gemm_psi<<<cdiv(M, 128), TB, 0, stream>>>(
        mP, mE, rowfac, W2f, b2f, mC, efeat_new, nullptr, M, 1);
}

// Round 8
// 406.585 us; speedup vs baseline: 14.8123x; 1.1142x over previous
//
#include <hip/hip_runtime.h>

#define D 128
#define SCAN_BLK 2048   // 256 threads * 8 elems
#define BTILE 4096      // items per bucket_pass block (16/thread)

typedef __bf16 bf16;
typedef __attribute__((ext_vector_type(4))) __bf16 bf16x4;
typedef __attribute__((ext_vector_type(8))) __bf16 bf16x8;
typedef __attribute__((ext_vector_type(4))) float f32x4;

__device__ __forceinline__ int pick4(int4 v, int r) {
    return r == 0 ? v.x : r == 1 ? v.y : r == 2 ? v.z : v.w;
}

// ---------------- fp32 -> bf16 convert (float4/lane) -------------------------------------
__global__ __launch_bounds__(256) void cvt_bf16(
    const float* __restrict__ in, bf16* __restrict__ out, int n4)
{
    int i = blockIdx.x * 256 + threadIdx.x;
    if (i >= n4) return;
    float4 f = ((const float4*)in)[i];
    bf16x4 v = { (bf16)f.x, (bf16)f.y, (bf16)f.z, (bf16)f.w };
    ((bf16x4*)out)[i] = v;
}

// ---------------- weight folding: W1f = Wv@W_psi1 (128x256), b1f = Wv@b1; same for We/W2 --
__global__ __launch_bounds__(256) void wfold(
    const float* __restrict__ Wv, const float* __restrict__ W1, const float* __restrict__ b1,
    const float* __restrict__ We, const float* __restrict__ W2, const float* __restrict__ b2,
    float* __restrict__ W1f, float* __restrict__ b1f,
    float* __restrict__ W2f, float* __restrict__ b2f)
{
    int gid = blockIdx.x * 256 + threadIdx.x;
    if (gid < 65536) {
        int which = gid >> 15;
        int i = (gid >> 8) & 127;
        int j = gid & 255;
        const float* A = which ? We : Wv;
        const float* B = which ? W2 : W1;
        float s = 0.0f;
        for (int k = 0; k < 128; ++k) s += A[i * 128 + k] * B[k * 256 + j];
        (which ? W2f : W1f)[i * 256 + j] = s;
    } else if (gid < 65536 + 256) {
        int t = gid - 65536, which = t >> 7, i = t & 127;
        const float* A = which ? We : Wv;
        const float* B = which ? b2 : b1;
        float s = 0.0f;
        for (int k = 0; k < 128; ++k) s += A[i * 128 + k] * B[k];
        (which ? b2f : b1f)[i] = s;
    }
}

// ---------------- MFMA GEMM (K=128): outH[r,i] = X[r,:]@W[i,:]  ---------------------------
__global__ __launch_bounds__(256) void gemm_mfma(
    const bf16* __restrict__ X, const float* __restrict__ W, int ldw,
    bf16* __restrict__ outH, int R)
{
    __shared__ __align__(16) bf16 Ws[D * D];
    const int t = threadIdx.x;
    for (int g = t; g < D * 16; g += 256) {
        int row = g >> 4, blk = g & 15;
        const float* src = W + (size_t)row * ldw + blk * 8;
        float4 f0 = *(const float4*)(src);
        float4 f1 = *(const float4*)(src + 4);
        bf16x8 v = { (bf16)f0.x, (bf16)f0.y, (bf16)f0.z, (bf16)f0.w,
                     (bf16)f1.x, (bf16)f1.y, (bf16)f1.z, (bf16)f1.w };
        *(bf16x8*)(&Ws[row * D + (blk ^ (row & 15)) * 8]) = v;
    }
    __syncthreads();

    const int lane = t & 63, wave = t >> 6;
    const int lrow = lane & 15, lk8 = lane >> 4;
    const int r0 = blockIdx.x * 128 + wave * 32;

    f32x4 acc[2][8] = {};
    for (int ks = 0; ks < 4; ++ks) {
        bf16x8 a[2];
#pragma unroll
        for (int mf = 0; mf < 2; ++mf) {
            int r = r0 + mf * 16 + lrow;
            if (r > R - 1) r = R - 1;
            a[mf] = *(const bf16x8*)(X + (size_t)r * D + ks * 32 + lk8 * 8);
        }
        bf16x8 b[8];
#pragma unroll
        for (int nf = 0; nf < 8; ++nf) {
            int row = nf * 16 + lrow;
            int blk = ks * 4 + lk8;
            b[nf] = *(const bf16x8*)(&Ws[row * D + (blk ^ (row & 15)) * 8]);
        }
#pragma unroll
        for (int mf = 0; mf < 2; ++mf)
#pragma unroll
            for (int nf = 0; nf < 8; ++nf)
                acc[mf][nf] = __builtin_amdgcn_mfma_f32_16x16x32_bf16(a[mf], b[nf], acc[mf][nf], 0, 0, 0);
    }

#pragma unroll
    for (int mf = 0; mf < 2; ++mf) {
        int rbase = r0 + mf * 16 + (lane >> 4) * 4;
#pragma unroll
        for (int e = 0; e < 4; ++e) {
            int r = rbase + e;
            if (r >= R) continue;
#pragma unroll
            for (int nf = 0; nf < 8; ++nf)
                outH[(size_t)r * D + nf * 16 + (lane & 15)] = (bf16)acc[mf][nf][e];
        }
    }
}

// ---------------- PSI MFMA GEMM (K=256): out = act([X1 ; X2*fac] @ Wf^T + fac*bf + addH) --
__global__ __launch_bounds__(256) void gemm_psi(
    const bf16* __restrict__ X1, const bf16* __restrict__ X2,
    const float* __restrict__ rowfac, const float* __restrict__ Wf,
    const float* __restrict__ bf_, const bf16* __restrict__ addH,
    float* __restrict__ outF, bf16* __restrict__ outH, int R, int doRelu)
{
    __shared__ __align__(16) bf16 Ws[D * 256];   // 64 KB
    const int t = threadIdx.x;
    for (int g = t; g < D * 32; g += 256) {
        int row = g >> 5, blk = g & 31;
        const float* src = Wf + (size_t)row * 256 + blk * 8;
        float4 f0 = *(const float4*)(src);
        float4 f1 = *(const float4*)(src + 4);
        bf16x8 v = { (bf16)f0.x, (bf16)f0.y, (bf16)f0.z, (bf16)f0.w,
                     (bf16)f1.x, (bf16)f1.y, (bf16)f1.z, (bf16)f1.w };
        *(bf16x8*)(&Ws[row * 256 + (blk ^ (row & 15)) * 8]) = v;
    }
    __syncthreads();

    const int lane = t & 63, wave = t >> 6;
    const int lrow = lane & 15, lk8 = lane >> 4;
    const int r0 = blockIdx.x * 128 + wave * 32;

    int rr[2]; float fac[2];
#pragma unroll
    for (int mf = 0; mf < 2; ++mf) {
        rr[mf] = min(r0 + mf * 16 + lrow, R - 1);
        fac[mf] = rowfac[rr[mf]];
    }

    f32x4 acc[2][8] = {};
    for (int ks = 0; ks < 8; ++ks) {
        bf16x8 a[2];
#pragma unroll
        for (int mf = 0; mf < 2; ++mf) {
            if (ks < 4) {
                a[mf] = *(const bf16x8*)(X1 + (size_t)rr[mf] * D + ks * 32 + lk8 * 8);
            } else {
                bf16x8 m = *(const bf16x8*)(X2 + (size_t)rr[mf] * D + (ks - 4) * 32 + lk8 * 8);
#pragma unroll
                for (int c = 0; c < 8; ++c) a[mf][c] = (bf16)((float)m[c] * fac[mf]);
            }
        }
        bf16x8 b[8];
#pragma unroll
        for (int nf = 0; nf < 8; ++nf) {
            int row = nf * 16 + lrow;
            int blk = ks * 4 + lk8;
            b[nf] = *(const bf16x8*)(&Ws[row * 256 + (blk ^ (row & 15)) * 8]);
        }
#pragma unroll
        for (int mf = 0; mf < 2; ++mf)
#pragma unroll
            for (int nf = 0; nf < 8; ++nf)
                acc[mf][nf] = __builtin_amdgcn_mfma_f32_16x16x32_bf16(a[mf], b[nf], acc[mf][nf], 0, 0, 0);
    }

#pragma unroll
    for (int mf = 0; mf < 2; ++mf) {
        int rbase = r0 + mf * 16 + (lane >> 4) * 4;
#pragma unroll
        for (int e = 0; e < 4; ++e) {
            int r = rbase + e;
            if (r >= R) continue;
            float bs = rowfac[r];
#pragma unroll
            for (int nf = 0; nf < 8; ++nf) {
                int col = nf * 16 + (lane & 15);
                float v = acc[mf][nf][e] + bs * bf_[col];
                if (addH) v += (float)addH[(size_t)r * D + col];
                if (doRelu) v = fmaxf(v, 0.0f);
                if (outF) outF[(size_t)r * D + col] = v;
                if (outH) outH[(size_t)r * D + col] = (bf16)v;
            }
        }
    }
}

// ---------------- merged histogram over all 4 key arrays ---------------------------------
__global__ __launch_bounds__(256) void hist_all(
    const int* __restrict__ ie, const int* __restrict__ iv,
    const int* __restrict__ er, const int* __restrict__ vr,
    int E, int nnzE, int nnzV, int bV, int bEr, int bVr, int* __restrict__ cnt)
{
    int gid = blockIdx.x * 256 + threadIdx.x;
    if (gid < E) atomicAdd(cnt + ie[gid], 1);
    else if (gid < 2 * E) atomicAdd(cnt + bV + iv[gid - E], 1);
    else if (gid < 2 * E + nnzE) atomicAdd(cnt + bEr + er[gid - 2 * E], 1);
    else if (gid < 2 * E + nnzE + nnzV) atomicAdd(cnt + bVr + vr[gid - 2 * E - nnzE], 1);
}

// ---------------- bucket pass: append (lk<<17|gs) into each bucket's slot range ----------
// Tile of BTILE items; LDS per-bucket counts -> one global atomic reserve per (tile,bucket);
// writes are contiguous runs per bucket -> low write amplification.
__global__ __launch_bounds__(256) void bucket_pass(
    const int* __restrict__ ie, const int* __restrict__ iv,
    const int* __restrict__ er_r, const int* __restrict__ er_c, const float* __restrict__ er_v,
    const int* __restrict__ vr_r, const int* __restrict__ vr_c, const float* __restrict__ vr_v,
    int E, int nnzE, int nnzV,
    int4 rbOff, int4 rbb, int4 SHv, int NB,
    const int* __restrict__ off_all, int* __restrict__ bcur,
    int* __restrict__ bkT, float* __restrict__ wT_sh)
{
    __shared__ int h_cnt[1024];
    __shared__ int h_gb[1024];
    __shared__ int h_bs[1024];
    const int t = threadIdx.x;
    const int TH = 2 * E + nnzE + nnzV;
    const size_t base = (size_t)blockIdx.x * BTILE;
    for (int i = t; i < NB; i += 256) h_cnt[i] = 0;
    __syncthreads();

    int pk[16], bl[16]; float wv[16];
#pragma unroll
    for (int j = 0; j < 16; ++j) {
        int gid = (int)base + j * 256 + t;
        bl[j] = -1; wv[j] = 0.0f;
        if (gid >= TH) continue;
        int key, gs, r; float w = 0.0f;
        if (gid < E)               { key = ie[gid]; gs = iv[gid]; r = 0; }
        else if (gid < 2 * E)      { int i2 = gid - E; key = iv[i2]; gs = ie[i2]; r = 1; }
        else if (gid < 2 * E + nnzE) { int i2 = gid - 2 * E; key = er_r[i2]; gs = er_c[i2]; w = er_v[i2]; r = 2; }
        else                       { int i2 = gid - 2 * E - nnzE; key = vr_r[i2]; gs = vr_c[i2]; w = vr_v[i2]; r = 3; }
        int sh = pick4(SHv, r);
        int b = pick4(rbb, r) + (key >> sh);
        int lk = key & ((1 << sh) - 1);
        pk[j] = (lk << 17) | gs;
        int lr = atomicAdd(&h_cnt[b], 1);
        bl[j] = (b << 12) | lr;
        wv[j] = w;
    }
    __syncthreads();

    for (int b = t; b < NB; b += 256) {
        int c = h_cnt[b];
        if (c > 0) {
            int r = (b >= rbb.w) ? 3 : (b >= rbb.z) ? 2 : (b >= rbb.y) ? 1 : 0;
            int bloc = b - pick4(rbb, r);
            h_bs[b] = off_all[pick4(rbOff, r) + (bloc << pick4(SHv, r))];
            h_gb[b] = atomicAdd(&bcur[b], c);
        }
    }
    __syncthreads();

#pragma unroll
    for (int j = 0; j < 16; ++j) {
        if (bl[j] < 0) continue;
        int b = bl[j] >> 12, lr = bl[j] & 4095;
        int pos = h_bs[b] + h_gb[b] + lr;
        bkT[pos] = pk[j];
        if (pos >= 2 * E) wT_sh[pos] = wv[j];
    }
}

// ---------------- finalize: per bucket, place items at exact in-segment slots ------------
__global__ __launch_bounds__(256) void finalize_pass(
    int E, int4 rbOff, int4 rbb, int4 SHv, int4 Kkeys,
    const int* __restrict__ off_all, const int* __restrict__ bkT,
    const float* __restrict__ wT_sh,
    int* __restrict__ gs_all, float* __restrict__ w_sh)
{
    __shared__ int off_l[1025];
    __shared__ int cnt_l[1024];
    const int b = blockIdx.x, t = threadIdx.x;
    const int r = (b >= rbb.w) ? 3 : (b >= rbb.z) ? 2 : (b >= rbb.y) ? 1 : 0;
    const int bloc = b - pick4(rbb, r);
    const int sh = pick4(SHv, r);
    const int rb = pick4(rbOff, r);
    const int K = pick4(Kkeys, r);
    const int k0 = bloc << sh;
    const int nk = min(1 << sh, K - k0);
    for (int i = t; i <= nk; i += 256) off_l[i] = off_all[rb + k0 + i];
    for (int i = t; i < nk; i += 256) cnt_l[i] = 0;
    __syncthreads();
    const int s0 = off_l[0], s1 = off_l[nk];
    const bool hasw = (r >= 2);
    for (int i = s0 + t; i < s1; i += 256) {
        int p = bkT[i];
        int lk = p >> 17, gs = p & 0x1FFFF;
        int lpos = off_l[lk] - s0 + atomicAdd(&cnt_l[lk], 1);
        gs_all[s0 + lpos] = gs;
        if (hasw) w_sh[s0 + lpos] = wT_sh[i];
    }
}

// ---------------- batched hierarchical exclusive scan ------------------------------------
__global__ __launch_bounds__(256) void scan_pass1(
    const int* __restrict__ in, int n, int* __restrict__ bsum)
{
    int b = blockIdx.x, t = threadIdx.x;
    int base = b * SCAN_BLK + t * 8;
    int s = 0;
#pragma unroll
    for (int j = 0; j < 8; ++j) { int i = base + j; if (i < n) s += in[i]; }
#pragma unroll
    for (int of = 1; of < 64; of <<= 1) s += __shfl_xor(s, of, 64);
    __shared__ int wsum[4];
    if ((t & 63) == 0) wsum[t >> 6] = s;
    __syncthreads();
    if (t == 0) bsum[b] = wsum[0] + wsum[1] + wsum[2] + wsum[3];
}

__global__ __launch_bounds__(256) void scan_pass2(int* __restrict__ bsum, int nb)
{
    __shared__ int carry, wsum[4], wpre[5];
    int t = threadIdx.x, wid = t >> 6, lane = t & 63;
    if (t == 0) carry = 0;
    __syncthreads();
    for (int base = 0; base < nb; base += 256) {
        int x = (base + t < nb) ? bsum[base + t] : 0;
        int v = x;
#pragma unroll
        for (int of = 1; of < 64; of <<= 1) {
            int u = __shfl_up(v, of, 64);
            if (lane >= of) v += u;
        }
        if (lane == 63) wsum[wid] = v;
        __syncthreads();
        if (t == 0) { int s = carry; for (int i = 0; i < 4; ++i) { wpre[i] = s; s += wsum[i]; } wpre[4] = s; }
        __syncthreads();
        if (base + t < nb) bsum[base + t] = wpre[wid] + v - x;
        __syncthreads();
        if (t == 0) carry = wpre[4];
        __syncthreads();
    }
}

__global__ __launch_bounds__(256) void scan_pass3(
    const int* __restrict__ in, int n, const int* __restrict__ bsum, int* __restrict__ out)
{
    int b = blockIdx.x, t = threadIdx.x, wid = t >> 6, lane = t & 63;
    int base = b * SCAN_BLK + t * 8;
    int x[8], s = 0;
#pragma unroll
    for (int j = 0; j < 8; ++j) { int i = base + j; x[j] = (i < n) ? in[i] : 0; s += x[j]; }
    int v = s;
#pragma unroll
    for (int of = 1; of < 64; of <<= 1) {
        int u = __shfl_up(v, of, 64);
        if (lane >= of) v += u;
    }
    __shared__ int wsum[4], wpre[4];
    if (lane == 63) wsum[wid] = v;
    __syncthreads();
    if (t == 0) { int acc = 0; for (int i = 0; i < 4; ++i) { wpre[i] = acc; acc += wsum[i]; } }
    __syncthreads();
    int pre = bsum[b] + wpre[wid] + (v - s);
#pragma unroll
    for (int j = 0; j < 8; ++j) { int i = base + j; if (i < n) out[i] = pre; pre += x[j]; }
}

// ---------------- CSR gather segment-reduce (bf16 src, fp32 accum, de-indirected) --------
// KIND 0: spmm   w=w_sh[slot];  out = acc (+auxH row)
// KIND 1: mean   w=gscale[gs];  out = acc*rs
// KIND 2: mean   w=1;           outH = bf16(relu(acc*rs)), outF = fp32(relu(acc*rs))
// KIND 6: mean   w=1;           out = acc*rs; rowfac=[cnt>0]
// KIND 7: mean   w=gscale[gs];  out = acc*rs; outH2 = (unweighted mean of src2); rowfac=sd*rs
template<int KIND>
__global__ __launch_bounds__(256) void seg_gather(
    const bf16* __restrict__ src, const bf16* __restrict__ src2,
    const int* __restrict__ off, const int* __restrict__ gs_all,
    const float* __restrict__ w_sh, const float* __restrict__ gscale,
    const bf16* __restrict__ auxH,
    bf16* __restrict__ outH, bf16* __restrict__ outH2,
    float* __restrict__ outF, float* __restrict__ rowfac, int R)
{
    int r = blockIdx.x * 4 + (threadIdx.x >> 6);
    if (r >= R) return;
    const int lane = threadIdx.x & 63;
    const int q = lane >> 4, lc = lane & 15;
    const int s0 = off[r], s1 = off[r + 1];
    float acc[8] = {}, acc2[8] = {};
    float sd = 0.0f;
    for (int base = s0; base < s1; base += 64) {
        const int nchunk = min(64, s1 - base);
        int mygs = 0; float myw = 0.0f;
        if (base + lane < s1) {
            mygs = gs_all[base + lane];
            if (KIND == 0) myw = w_sh[base + lane];
            else if (KIND == 1 || KIND == 7) myw = gscale[mygs];
            else myw = 1.0f;
        }
        for (int j = 0; j < nchunk; j += 4) {
            int g0 = __shfl(mygs, j, 64),     g1 = __shfl(mygs, j + 1, 64);
            int g2 = __shfl(mygs, j + 2, 64), g3 = __shfl(mygs, j + 3, 64);
            float w0 = __shfl(myw, j, 64),     w1 = __shfl(myw, j + 1, 64);
            float w2 = __shfl(myw, j + 2, 64), w3 = __shfl(myw, j + 3, 64);
            int gs  = q < 2 ? (q ? g1 : g0) : (q == 2 ? g2 : g3);
            float w = q < 2 ? (q ? w1 : w0) : (q == 2 ? w2 : w3);
            bf16x8 v = *(const bf16x8*)(src + (size_t)gs * D + lc * 8);
#pragma unroll
            for (int c = 0; c < 8; ++c) acc[c] += (float)v[c] * w;
            if (KIND == 7) {
                float wv = (j + q < nchunk) ? 1.0f : 0.0f;
                bf16x8 u = *(const bf16x8*)(src2 + (size_t)gs * D + lc * 8);
#pragma unroll
                for (int c = 0; c < 8; ++c) acc2[c] += (float)u[c] * wv;
                sd += w;
            }
        }
    }
#pragma unroll
    for (int c = 0; c < 8; ++c) {
        acc[c] += __shfl_xor(acc[c], 16, 64);
        acc[c] += __shfl_xor(acc[c], 32, 64);
    }
    if (KIND == 7) {
#pragma unroll
        for (int c = 0; c < 8; ++c) {
            acc2[c] += __shfl_xor(acc2[c], 16, 64);
            acc2[c] += __shfl_xor(acc2[c], 32, 64);
        }
        sd += __shfl_xor(sd, 16, 64);
        sd += __shfl_xor(sd, 32, 64);
    }
    const int cnt = s1 - s0;
    const float rs = 1.0f / (float)max(cnt, 1);

    if (KIND == 0) {
        if (q == 0) {
            float o[8];
#pragma unroll
            for (int c = 0; c < 8; ++c) o[c] = acc[c];
            if (auxH) {
                bf16x8 a = *(const bf16x8*)(auxH + (size_t)r * D + lc * 8);
#pragma unroll
                for (int c = 0; c < 8; ++c) o[c] += (float)a[c];
            }
            bf16x8 wv;
#pragma unroll
            for (int c = 0; c < 8; ++c) wv[c] = (bf16)o[c];
            *(bf16x8*)(outH + (size_t)r * D + lc * 8) = wv;
        }
    } else if (KIND == 1 || KIND == 6) {
        if (q == 0) {
            bf16x8 wv;
#pragma unroll
            for (int c = 0; c < 8; ++c) wv[c] = (bf16)(acc[c] * rs);
            *(bf16x8*)(outH + (size_t)r * D + lc * 8) = wv;
        }
        if (KIND == 6 && lane == 0) rowfac[r] = (cnt > 0) ? 1.0f : 0.0f;
    } else if (KIND == 2) {
        if (q == 0) {
            bf16x8 wv;
#pragma unroll
            for (int c = 0; c < 8; ++c) wv[c] = (bf16)fmaxf(acc[c] * rs, 0.0f);
            *(bf16x8*)(outH + (size_t)r * D + lc * 8) = wv;
        } else if (q == 1) {
            float4 o0 = { fmaxf(acc[0] * rs, 0.0f), fmaxf(acc[1] * rs, 0.0f),
                          fmaxf(acc[2] * rs, 0.0f), fmaxf(acc[3] * rs, 0.0f) };
            float4 o1 = { fmaxf(acc[4] * rs, 0.0f), fmaxf(acc[5] * rs, 0.0f),
                          fmaxf(acc[6] * rs, 0.0f), fmaxf(acc[7] * rs, 0.0f) };
            *(float4*)(outF + (size_t)r * D + lc * 8) = o0;
            *(float4*)(outF + (size_t)r * D + lc * 8 + 4) = o1;
        }
    } else {  // KIND 7
        if (q == 0) {
            bf16x8 wv;
#pragma unroll
            for (int c = 0; c < 8; ++c) wv[c] = (bf16)(acc[c] * rs);
            *(bf16x8*)(outH + (size_t)r * D + lc * 8) = wv;
        } else if (q == 1) {
            bf16x8 wv;
#pragma unroll
            for (int c = 0; c < 8; ++c) wv[c] = (bf16)(acc2[c] * rs);
            *(bf16x8*)(outH2 + (size_t)r * D + lc * 8) = wv;
        }
        if (lane == 0) rowfac[r] = sd * rs;
    }
}

extern "C" void kernel_launch(void* const* d_in, const int* in_sizes, int n_in,
                              void* d_out, int out_size, void* d_ws, size_t ws_size,
                              hipStream_t stream) {
    const float* vfeat  = (const float*)d_in[0];
    const float* efeat  = (const float*)d_in[1];
    const float* invDV  = (const float*)d_in[2];
    const float* invDE  = (const float*)d_in[3];
    const int*   inc_v  = (const int*)d_in[4];
    const int*   inc_e  = (const int*)d_in[5];
    const int*   eM_row = (const int*)d_in[6];
    const int*   eM_col = (const int*)d_in[7];
    const float* eM_val = (const float*)d_in[8];
    const int*   vM_row = (const int*)d_in[9];
    const int*   vM_col = (const int*)d_in[10];
    const float* vM_val = (const float*)d_in[11];
    const float* W_psi1 = (const float*)d_in[12];
    const float* b_psi1 = (const float*)d_in[13];
    const float* W_psi2 = (const float*)d_in[14];
    const float* b_psi2 = (const float*)d_in[15];
    const float* W_v    = (const float*)d_in[16];
    const float* W_e    = (const float*)d_in[17];

    const int N = in_sizes[0] / D;
    const int M = in_sizes[1] / D;
    const int E = in_sizes[4];
    const int nnzE = in_sizes[6];
    const int nnzV = in_sizes[9];
    const int TH = 2 * E + nnzE + nnzV;

    float* out = (float*)d_out;
    float* vfeat_new = out;                     // N*D
    float* efeat_new = out + (size_t)N * D;     // M*D

    const int T = 2 * M + 2 * N + 4;
    const int nbScan = (T + SCAN_BLK - 1) / SCAN_BLK;

    // bucket geometry (targets ~5-6k items/bucket)
    const int shE = 8, shV = 10, shEr = 9, shVr = 10;
    auto cdiv = [](int a, int b) { return (a + b - 1) / b; };
    const int nbE  = cdiv(M, 1 << shE);
    const int nbV  = cdiv(N, 1 << shV);
    const int nbEr = cdiv(M, 1 << shEr);
    const int nbVr = cdiv(N, 1 << shVr);
    const int NB = nbE + nbV + nbEr + nbVr;   // 315 for the bench sizes (<=1024 required)
    const int4 rbb   = { 0, nbE, nbE + nbV, nbE + nbV + nbEr };
    const int4 SHv   = { shE, shV, shEr, shVr };
    const int4 Kkeys = { M, N, M, N };
    const int bV  = M + 1;
    const int bEr = bV + (N + 1);
    const int bVr = bEr + (M + 1);
    const int4 rbOff = { 0, bV, bEr, bVr };

    // workspace layout (bf16 first, 16B-aligned sections)
    bf16* nA  = (bf16*)d_ws;                    // N*D  vfeatH
    bf16* nB  = nA + (size_t)N * D;             // N*D  vf2preW
    bf16* nC  = nB + (size_t)N * D;             // N*D  vf2W -> vnewH
    bf16* mE  = nC + (size_t)N * D;             // M*D  efeatH
    bf16* mWe = mE + (size_t)M * D;             // M*D  efW_e -> A' (mA)
    bf16* mV  = mWe + (size_t)M * D;            // M*D  efW_v
    bf16* mB  = mV + (size_t)M * D;             // M*D  _efeatV
    bf16* mC  = mB + (size_t)M * D;             // M*D  ef3preW
    bf16* mP  = mC + (size_t)M * D;             // M*D  psi gather out (1 then 2)
    bf16* mA  = mWe;                            // alias: A' after efW_e dead
    float* W1f = (float*)(mP + (size_t)M * D);  // 128*256
    float* W2f = W1f + 128 * 256;               // 128*256
    float* b1f = W2f + 128 * 256;               // 128
    float* b2f = b1f + 128;                     // 128
    float* rowfac = b2f + 128;                  // M
    int* cnt_all = (int*)(rowfac + M);          // T (scanned in-place -> off_all)
    int* bcur    = cnt_all + T;                 // NB (memset with cnt_all)
    int* bsum    = bcur + NB;                   // nbScan+1
    int* gs_all  = bsum + nbScan + 1;           // TH (final)
    int* bkT     = gs_all + TH;                 // TH (staging)
    float* wfin  = (float*)(bkT + TH);          // nnzE+nnzV (final)
    float* wTst  = wfin + (nnzE + nnzV);        // nnzE+nnzV (staging)
    float* w_sh  = wfin - (size_t)2 * E;        // final, indexed by slot >= 2E
    float* wT_sh = wTst - (size_t)2 * E;        // staging, indexed by slot >= 2E

    int* off_all = cnt_all;
    int* offE  = off_all;
    int* offV  = off_all + bV;
    int* offEr = off_all + bEr;
    int* offVr = off_all + bVr;

    const dim3 TB(256);

    // ---- CSR build: hist -> scan -> bucketed append -> block-local finalize ----
    hipMemsetAsync(cnt_all, 0, (size_t)(T + NB) * 4, stream);
    hist_all<<<cdiv(TH, 256), TB, 0, stream>>>(inc_e, inc_v, eM_row, vM_row,
                                               E, nnzE, nnzV, bV, bEr, bVr, cnt_all);
    scan_pass1<<<nbScan, TB, 0, stream>>>(cnt_all, T, bsum);
    scan_pass2<<<1, TB, 0, stream>>>(bsum, nbScan);
    scan_pass3<<<nbScan, TB, 0, stream>>>(cnt_all, T, bsum, off_all);
    bucket_pass<<<cdiv(TH, BTILE), TB, 0, stream>>>(
        inc_e, inc_v, eM_row, eM_col, eM_val, vM_row, vM_col, vM_val,
        E, nnzE, nnzV, rbOff, rbb, SHv, NB, off_all, bcur, bkT, wT_sh);
    finalize_pass<<<NB, TB, 0, stream>>>(
        E, rbOff, rbb, SHv, Kkeys, off_all, bkT, wT_sh, gs_all, w_sh);

    // ---- bf16 inputs + folded weights ----
    cvt_bf16<<<cdiv(N * D / 4, 256), TB, 0, stream>>>(vfeat, nA, N * D / 4);
    cvt_bf16<<<cdiv(M * D / 4, 256), TB, 0, stream>>>(efeat, mE, M * D / 4);
    wfold<<<257, TB, 0, stream>>>(W_v, W_psi1, b_psi1, W_e, W_psi2, b_psi2,
                                  W1f, b1f, W2f, b2f);

    // ---- pipeline (fully in Wv/We-transformed space for the two chains) ----
    // efW_e = efeat @ W_e^T ; efW_v = efeat @ W_v^T
    gemm_mfma<<<cdiv(M, 128), TB, 0, stream>>>(mE, W_e, D, mWe, M);
    gemm_mfma<<<cdiv(M, 128), TB, 0, stream>>>(mE, W_v, D, mV, M);
    // vf2preW = mean_v(efW_e[inc_e] * invDE[inc_e]) -> nB
    seg_gather<1><<<cdiv(N, 4), TB, 0, stream>>>(
        mWe, nullptr, offV, gs_all, nullptr, invDE, nullptr, nB, nullptr, nullptr, nullptr, N);
    // vf2W = spmm_V(vf2preW) -> nC
    seg_gather<0><<<cdiv(N, 4), TB, 0, stream>>>(
        nB, nullptr, offVr, gs_all, w_sh, nullptr, nullptr, nC, nullptr, nullptr, nullptr, N);
    // FUSED psi1: mP = mean_w(vfeatH*dv); mC = ef3preW = mean(vf2W); rowfac = sd/cnt
    seg_gather<7><<<cdiv(M, 4), TB, 0, stream>>>(
        nA, nC, offE, gs_all, nullptr, invDV, nullptr, mP, mC, nullptr, rowfac, M);
    // A' = [mP ; mE*fac] @ W1f^T + fac*b1f -> mA (bf16)
    gemm_psi<<<cdiv(M, 128), TB, 0, stream>>>(
        mP, mE, rowfac, W1f, b1f, nullptr, nullptr, mA, M, 0);
    // _efeatV = spmm_E(A') + efW_v -> mB
    seg_gather<0><<<cdiv(M, 4), TB, 0, stream>>>(
        mA, nullptr, offEr, gs_all, w_sh, nullptr, mV, mB, nullptr, nullptr, nullptr, M);
    // vfeat_new = relu(mean_v(_efeatV)) -> d_out fp32 + nC bf16 (vf2W dead)
    seg_gather<2><<<cdiv(N, 4), TB, 0, stream>>>(
        mB, nullptr, offV, gs_all, nullptr, nullptr, nullptr, nC, nullptr, vfeat_new, nullptr, N);
    // psi2: mP = mean(vnewH); rowfac = [cnt>0]
    seg_gather<6><<<cdiv(M, 4), TB, 0, stream>>>(
        nC, nullptr, offE, gs_all, nullptr, nullptr, nullptr, mP, nullptr, nullptr, rowfac, M);
    // efeat_new = relu([mP ; mE*fac] @ W2f^T + fac*b2f + ef3preW) -> d_out
    gemm_psi<<<cdiv(M, 128), TB, 0, stream>>>(
        mP, mE, rowfac, W2f, b2f, mC, efeat_new, nullptr, M, 1);
}

// Round 9
// 345.196 us; speedup vs baseline: 17.4464x; 1.1778x over previous
//
#include <hip/hip_runtime.h>

#define D 128
#define BTILE 4096      // items per bucket/hist block (16/thread)

typedef __bf16 bf16;
typedef __attribute__((ext_vector_type(4))) __bf16 bf16x4;
typedef __attribute__((ext_vector_type(8))) __bf16 bf16x8;
typedef __attribute__((ext_vector_type(4))) float f32x4;

__device__ __forceinline__ int pick4(int4 v, int r) {
    return r == 0 ? v.x : r == 1 ? v.y : r == 2 ? v.z : v.w;
}

// ---------------- fp32 -> bf16 convert (float4/lane) -------------------------------------
__global__ __launch_bounds__(256) void cvt_bf16(
    const float* __restrict__ in, bf16* __restrict__ out, int n4)
{
    int i = blockIdx.x * 256 + threadIdx.x;
    if (i >= n4) return;
    float4 f = ((const float4*)in)[i];
    bf16x4 v = { (bf16)f.x, (bf16)f.y, (bf16)f.z, (bf16)f.w };
    ((bf16x4*)out)[i] = v;
}

// ---------------- weight folding: W1f = Wv@W_psi1 (128x256), b1f = Wv@b1; same for We/W2 --
__global__ __launch_bounds__(256) void wfold(
    const float* __restrict__ Wv, const float* __restrict__ W1, const float* __restrict__ b1,
    const float* __restrict__ We, const float* __restrict__ W2, const float* __restrict__ b2,
    float* __restrict__ W1f, float* __restrict__ b1f,
    float* __restrict__ W2f, float* __restrict__ b2f)
{
    int gid = blockIdx.x * 256 + threadIdx.x;
    if (gid < 65536) {
        int which = gid >> 15;
        int i = (gid >> 8) & 127;
        int j = gid & 255;
        const float* A = which ? We : Wv;
        const float* B = which ? W2 : W1;
        float s = 0.0f;
        for (int k = 0; k < 128; ++k) s += A[i * 128 + k] * B[k * 256 + j];
        (which ? W2f : W1f)[i * 256 + j] = s;
    } else if (gid < 65536 + 256) {
        int t = gid - 65536, which = t >> 7, i = t & 127;
        const float* A = which ? We : Wv;
        const float* B = which ? b2 : b1;
        float s = 0.0f;
        for (int k = 0; k < 128; ++k) s += A[i * 128 + k] * B[k];
        (which ? b2f : b1f)[i] = s;
    }
}

// ---------------- MFMA GEMM (K=128): outH[r,i] = X[r,:]@W[i,:]  ---------------------------
__global__ __launch_bounds__(256) void gemm_mfma(
    const bf16* __restrict__ X, const float* __restrict__ W, int ldw,
    bf16* __restrict__ outH, int R)
{
    __shared__ __align__(16) bf16 Ws[D * D];
    const int t = threadIdx.x;
    for (int g = t; g < D * 16; g += 256) {
        int row = g >> 4, blk = g & 15;
        const float* src = W + (size_t)row * ldw + blk * 8;
        float4 f0 = *(const float4*)(src);
        float4 f1 = *(const float4*)(src + 4);
        bf16x8 v = { (bf16)f0.x, (bf16)f0.y, (bf16)f0.z, (bf16)f0.w,
                     (bf16)f1.x, (bf16)f1.y, (bf16)f1.z, (bf16)f1.w };
        *(bf16x8*)(&Ws[row * D + (blk ^ (row & 15)) * 8]) = v;
    }
    __syncthreads();

    const int lane = t & 63, wave = t >> 6;
    const int lrow = lane & 15, lk8 = lane >> 4;
    const int r0 = blockIdx.x * 128 + wave * 32;

    f32x4 acc[2][8] = {};
    for (int ks = 0; ks < 4; ++ks) {
        bf16x8 a[2];
#pragma unroll
        for (int mf = 0; mf < 2; ++mf) {
            int r = r0 + mf * 16 + lrow;
            if (r > R - 1) r = R - 1;
            a[mf] = *(const bf16x8*)(X + (size_t)r * D + ks * 32 + lk8 * 8);
        }
        bf16x8 b[8];
#pragma unroll
        for (int nf = 0; nf < 8; ++nf) {
            int row = nf * 16 + lrow;
            int blk = ks * 4 + lk8;
            b[nf] = *(const bf16x8*)(&Ws[row * D + (blk ^ (row & 15)) * 8]);
        }
#pragma unroll
        for (int mf = 0; mf < 2; ++mf)
#pragma unroll
            for (int nf = 0; nf < 8; ++nf)
                acc[mf][nf] = __builtin_amdgcn_mfma_f32_16x16x32_bf16(a[mf], b[nf], acc[mf][nf], 0, 0, 0);
    }

#pragma unroll
    for (int mf = 0; mf < 2; ++mf) {
        int rbase = r0 + mf * 16 + (lane >> 4) * 4;
#pragma unroll
        for (int e = 0; e < 4; ++e) {
            int r = rbase + e;
            if (r >= R) continue;
#pragma unroll
            for (int nf = 0; nf < 8; ++nf)
                outH[(size_t)r * D + nf * 16 + (lane & 15)] = (bf16)acc[mf][nf][e];
        }
    }
}

// ---------------- PSI MFMA GEMM (K=256): out = act([X1 ; X2*fac] @ Wf^T + fac*bf + addH) --
__global__ __launch_bounds__(256) void gemm_psi(
    const bf16* __restrict__ X1, const bf16* __restrict__ X2,
    const float* __restrict__ rowfac, const float* __restrict__ Wf,
    const float* __restrict__ bf_, const bf16* __restrict__ addH,
    float* __restrict__ outF, bf16* __restrict__ outH, int R, int doRelu)
{
    __shared__ __align__(16) bf16 Ws[D * 256];   // 64 KB
    const int t = threadIdx.x;
    for (int g = t; g < D * 32; g += 256) {
        int row = g >> 5, blk = g & 31;
        const float* src = Wf + (size_t)row * 256 + blk * 8;
        float4 f0 = *(const float4*)(src);
        float4 f1 = *(const float4*)(src + 4);
        bf16x8 v = { (bf16)f0.x, (bf16)f0.y, (bf16)f0.z, (bf16)f0.w,
                     (bf16)f1.x, (bf16)f1.y, (bf16)f1.z, (bf16)f1.w };
        *(bf16x8*)(&Ws[row * 256 + (blk ^ (row & 15)) * 8]) = v;
    }
    __syncthreads();

    const int lane = t & 63, wave = t >> 6;
    const int lrow = lane & 15, lk8 = lane >> 4;
    const int r0 = blockIdx.x * 128 + wave * 32;

    int rr[2]; float fac[2];
#pragma unroll
    for (int mf = 0; mf < 2; ++mf) {
        rr[mf] = min(r0 + mf * 16 + lrow, R - 1);
        fac[mf] = rowfac[rr[mf]];
    }

    f32x4 acc[2][8] = {};
    for (int ks = 0; ks < 8; ++ks) {
        bf16x8 a[2];
#pragma unroll
        for (int mf = 0; mf < 2; ++mf) {
            if (ks < 4) {
                a[mf] = *(const bf16x8*)(X1 + (size_t)rr[mf] * D + ks * 32 + lk8 * 8);
            } else {
                bf16x8 m = *(const bf16x8*)(X2 + (size_t)rr[mf] * D + (ks - 4) * 32 + lk8 * 8);
#pragma unroll
                for (int c = 0; c < 8; ++c) a[mf][c] = (bf16)((float)m[c] * fac[mf]);
            }
        }
        bf16x8 b[8];
#pragma unroll
        for (int nf = 0; nf < 8; ++nf) {
            int row = nf * 16 + lrow;
            int blk = ks * 4 + lk8;
            b[nf] = *(const bf16x8*)(&Ws[row * 256 + (blk ^ (row & 15)) * 8]);
        }
#pragma unroll
        for (int mf = 0; mf < 2; ++mf)
#pragma unroll
            for (int nf = 0; nf < 8; ++nf)
                acc[mf][nf] = __builtin_amdgcn_mfma_f32_16x16x32_bf16(a[mf], b[nf], acc[mf][nf], 0, 0, 0);
    }

#pragma unroll
    for (int mf = 0; mf < 2; ++mf) {
        int rbase = r0 + mf * 16 + (lane >> 4) * 4;
#pragma unroll
        for (int e = 0; e < 4; ++e) {
            int r = rbase + e;
            if (r >= R) continue;
            float bs = rowfac[r];
#pragma unroll
            for (int nf = 0; nf < 8; ++nf) {
                int col = nf * 16 + (lane & 15);
                float v = acc[mf][nf][e] + bs * bf_[col];
                if (addH) v += (float)addH[(size_t)r * D + col];
                if (doRelu) v = fmaxf(v, 0.0f);
                if (outF) outF[(size_t)r * D + col] = v;
                if (outH) outH[(size_t)r * D + col] = (bf16)v;
            }
        }
    }
}

// ---------------- coarse histogram: per-block LDS hist over NB buckets -------------------
__global__ __launch_bounds__(256) void coarse_hist(
    const int* __restrict__ ie, const int* __restrict__ iv,
    const int* __restrict__ er, const int* __restrict__ vr,
    int E, int nnzE, int nnzV, int4 rbb, int4 SHv, int NB, int* __restrict__ cnt_c)
{
    __shared__ int h[1024];
    const int t = threadIdx.x;
    const int TH = 2 * E + nnzE + nnzV;
    for (int i = t; i < NB; i += 256) h[i] = 0;
    __syncthreads();
    const int base = blockIdx.x * BTILE;
#pragma unroll
    for (int j = 0; j < 16; ++j) {
        int gid = base + j * 256 + t;
        if (gid >= TH) break;
        int key, r;
        if (gid < E)                 { key = ie[gid]; r = 0; }
        else if (gid < 2 * E)        { key = iv[gid - E]; r = 1; }
        else if (gid < 2 * E + nnzE) { key = er[gid - 2 * E]; r = 2; }
        else                         { key = vr[gid - 2 * E - nnzE]; r = 3; }
        atomicAdd(&h[pick4(rbb, r) + (key >> pick4(SHv, r))], 1);
    }
    __syncthreads();
    for (int i = t; i < NB; i += 256) if (h[i]) atomicAdd(&cnt_c[i], h[i]);
}

// ---------------- small single-block exclusive scan: out[0..n], out[n]=total -------------
__global__ __launch_bounds__(256) void scan_small(
    const int* __restrict__ in, int n, int* __restrict__ out)
{
    __shared__ int carry, wsum[4], wpre[5];
    int t = threadIdx.x, wid = t >> 6, lane = t & 63;
    if (t == 0) carry = 0;
    __syncthreads();
    for (int base = 0; base < n; base += 256) {
        int x = (base + t < n) ? in[base + t] : 0;
        int v = x;
#pragma unroll
        for (int of = 1; of < 64; of <<= 1) {
            int u = __shfl_up(v, of, 64);
            if (lane >= of) v += u;
        }
        if (lane == 63) wsum[wid] = v;
        __syncthreads();
        if (t == 0) { int s = carry; for (int i = 0; i < 4; ++i) { wpre[i] = s; s += wsum[i]; } wpre[4] = s; }
        __syncthreads();
        if (base + t < n) out[base + t] = wpre[wid] + v - x;
        __syncthreads();
        if (t == 0) carry = wpre[4];
        __syncthreads();
    }
    if (t == 0) out[n] = carry;
}

// ---------------- bucket pass: append (lk<<17|gs) into each bucket's staging range -------
__global__ __launch_bounds__(256) void bucket_pass(
    const int* __restrict__ ie, const int* __restrict__ iv,
    const int* __restrict__ er_r, const int* __restrict__ er_c, const float* __restrict__ er_v,
    const int* __restrict__ vr_r, const int* __restrict__ vr_c, const float* __restrict__ vr_v,
    int E, int nnzE, int nnzV,
    int4 rbb, int4 SHv, int NB,
    const int* __restrict__ coarse_off, int* __restrict__ bcur,
    int* __restrict__ bkT, float* __restrict__ wT_sh)
{
    __shared__ int h_cnt[1024];
    __shared__ int h_gb[1024];
    const int t = threadIdx.x;
    const int TH = 2 * E + nnzE + nnzV;
    const int base = blockIdx.x * BTILE;
    for (int i = t; i < NB; i += 256) h_cnt[i] = 0;
    __syncthreads();

    int pk[16], bl[16]; float wv[16];
#pragma unroll
    for (int j = 0; j < 16; ++j) {
        int gid = base + j * 256 + t;
        bl[j] = -1; wv[j] = 0.0f;
        if (gid >= TH) continue;
        int key, gs, r; float w = 0.0f;
        if (gid < E)               { key = ie[gid]; gs = iv[gid]; r = 0; }
        else if (gid < 2 * E)      { int i2 = gid - E; key = iv[i2]; gs = ie[i2]; r = 1; }
        else if (gid < 2 * E + nnzE) { int i2 = gid - 2 * E; key = er_r[i2]; gs = er_c[i2]; w = er_v[i2]; r = 2; }
        else                       { int i2 = gid - 2 * E - nnzE; key = vr_r[i2]; gs = vr_c[i2]; w = vr_v[i2]; r = 3; }
        int sh = pick4(SHv, r);
        int b = pick4(rbb, r) + (key >> sh);
        int lk = key & ((1 << sh) - 1);
        pk[j] = (lk << 17) | gs;
        int lr = atomicAdd(&h_cnt[b], 1);
        bl[j] = (b << 12) | lr;
        wv[j] = w;
    }
    __syncthreads();

    for (int b = t; b < NB; b += 256) {
        int c = h_cnt[b];
        if (c > 0) h_gb[b] = coarse_off[b] + atomicAdd(&bcur[b], c);
    }
    __syncthreads();

#pragma unroll
    for (int j = 0; j < 16; ++j) {
        if (bl[j] < 0) continue;
        int b = bl[j] >> 12, lr = bl[j] & 4095;
        int pos = h_gb[b] + lr;
        bkT[pos] = pk[j];
        if (pos >= 2 * E) wT_sh[pos] = wv[j];
    }
}

// ---------------- finalize: per bucket local hist+scan -> off_all, gs_all, w -------------
__global__ __launch_bounds__(256) void finalize_pass(
    int E, int4 rbOff, int4 rbb, int4 SHv, int4 Kkeys,
    const int* __restrict__ coarse_off, const int* __restrict__ bkT,
    const float* __restrict__ wT_sh,
    int* __restrict__ off_all, int* __restrict__ gs_all, float* __restrict__ w_sh)
{
    __shared__ int cnt_l[1024];
    __shared__ int off_l[1025];
    __shared__ int wsum[4], wpre[4];
    const int b = blockIdx.x, t = threadIdx.x;
    const int r = (b >= rbb.w) ? 3 : (b >= rbb.z) ? 2 : (b >= rbb.y) ? 1 : 0;
    const int bloc = b - pick4(rbb, r);
    const int sh = pick4(SHv, r);
    const int rb = pick4(rbOff, r);
    const int K = pick4(Kkeys, r);
    const int k0 = bloc << sh;
    const int nk = min(1 << sh, K - k0);
    const int s0 = coarse_off[b], s1 = coarse_off[b + 1];
    for (int i = t; i < nk; i += 256) cnt_l[i] = 0;
    __syncthreads();
    for (int i = s0 + t; i < s1; i += 256)
        atomicAdd(&cnt_l[bkT[i] >> 17], 1);
    __syncthreads();
    // exclusive scan cnt_l[0..nk) -> off_l (4 elems/thread + wave + cross-wave)
    {
        const int wid = t >> 6, lane = t & 63;
        int x[4], s = 0;
#pragma unroll
        for (int j = 0; j < 4; ++j) { int i = t * 4 + j; x[j] = (i < nk) ? cnt_l[i] : 0; s += x[j]; }
        int v = s;
#pragma unroll
        for (int of = 1; of < 64; of <<= 1) {
            int u = __shfl_up(v, of, 64);
            if (lane >= of) v += u;
        }
        if (lane == 63) wsum[wid] = v;
        __syncthreads();
        if (t == 0) { int a = 0; for (int i = 0; i < 4; ++i) { wpre[i] = a; a += wsum[i]; } }
        __syncthreads();
        int pre = wpre[wid] + (v - s);
#pragma unroll
        for (int j = 0; j < 4; ++j) { int i = t * 4 + j; if (i < nk) off_l[i] = pre; pre += x[j]; }
        if (t == 0) off_l[nk] = s1 - s0;
    }
    __syncthreads();
    // write per-key global CSR offsets
    for (int i = t; i < nk; i += 256) off_all[rb + k0 + i] = s0 + off_l[i];
    if (t == 0 && k0 + nk == K) off_all[rb + K] = s1;
    for (int i = t; i < nk; i += 256) cnt_l[i] = 0;
    __syncthreads();
    const bool hasw = (r >= 2);
    for (int i = s0 + t; i < s1; i += 256) {
        int p = bkT[i];
        int lk = p >> 17, gs = p & 0x1FFFF;
        int lpos = off_l[lk] + atomicAdd(&cnt_l[lk], 1);
        gs_all[s0 + lpos] = gs;
        if (hasw) w_sh[s0 + lpos] = wT_sh[i];
    }
}

// ---------------- CSR gather segment-reduce (bf16 src, fp32 accum, de-indirected) --------
// KIND 0: spmm   w=w_sh[slot];  out = acc (+auxH row)
// KIND 1: mean   w=gscale[gs];  out = acc*rs
// KIND 2: mean   w=1;           outH = bf16(relu(acc*rs)), outF = fp32(relu(acc*rs))
// KIND 6: mean   w=1;           out = acc*rs; rowfac=[cnt>0]
// KIND 7: mean   w=gscale[gs];  out = acc*rs; outH2 = (unweighted mean of src2); rowfac=sd*rs
template<int KIND>
__global__ __launch_bounds__(256) void seg_gather(
    const bf16* __restrict__ src, const bf16* __restrict__ src2,
    const int* __restrict__ off, const int* __restrict__ gs_all,
    const float* __restrict__ w_sh, const float* __restrict__ gscale,
    const bf16* __restrict__ auxH,
    bf16* __restrict__ outH, bf16* __restrict__ outH2,
    float* __restrict__ outF, float* __restrict__ rowfac, int R)
{
    int r = blockIdx.x * 4 + (threadIdx.x >> 6);
    if (r >= R) return;
    const int lane = threadIdx.x & 63;
    const int q = lane >> 4, lc = lane & 15;
    const int s0 = off[r], s1 = off[r + 1];
    float acc[8] = {}, acc2[8] = {};
    float sd = 0.0f;
    for (int base = s0; base < s1; base += 64) {
        const int nchunk = min(64, s1 - base);
        int mygs = 0; float myw = 0.0f;
        if (base + lane < s1) {
            mygs = gs_all[base + lane];
            if (KIND == 0) myw = w_sh[base + lane];
            else if (KIND == 1 || KIND == 7) myw = gscale[mygs];
            else myw = 1.0f;
        }
        for (int j = 0; j < nchunk; j += 4) {
            int g0 = __shfl(mygs, j, 64),     g1 = __shfl(mygs, j + 1, 64);
            int g2 = __shfl(mygs, j + 2, 64), g3 = __shfl(mygs, j + 3, 64);
            float w0 = __shfl(myw, j, 64),     w1 = __shfl(myw, j + 1, 64);
            float w2 = __shfl(myw, j + 2, 64), w3 = __shfl(myw, j + 3, 64);
            int gs  = q < 2 ? (q ? g1 : g0) : (q == 2 ? g2 : g3);
            float w = q < 2 ? (q ? w1 : w0) : (q == 2 ? w2 : w3);
            bf16x8 v = *(const bf16x8*)(src + (size_t)gs * D + lc * 8);
#pragma unroll
            for (int c = 0; c < 8; ++c) acc[c] += (float)v[c] * w;
            if (KIND == 7) {
                float wv = (j + q < nchunk) ? 1.0f : 0.0f;
                bf16x8 u = *(const bf16x8*)(src2 + (size_t)gs * D + lc * 8);
#pragma unroll
                for (int c = 0; c < 8; ++c) acc2[c] += (float)u[c] * wv;
                sd += w;
            }
        }
    }
#pragma unroll
    for (int c = 0; c < 8; ++c) {
        acc[c] += __shfl_xor(acc[c], 16, 64);
        acc[c] += __shfl_xor(acc[c], 32, 64);
    }
    if (KIND == 7) {
#pragma unroll
        for (int c = 0; c < 8; ++c) {
            acc2[c] += __shfl_xor(acc2[c], 16, 64);
            acc2[c] += __shfl_xor(acc2[c], 32, 64);
        }
        sd += __shfl_xor(sd, 16, 64);
        sd += __shfl_xor(sd, 32, 64);
    }
    const int cnt = s1 - s0;
    const float rs = 1.0f / (float)max(cnt, 1);

    if (KIND == 0) {
        if (q == 0) {
            float o[8];
#pragma unroll
            for (int c = 0; c < 8; ++c) o[c] = acc[c];
            if (auxH) {
                bf16x8 a = *(const bf16x8*)(auxH + (size_t)r * D + lc * 8);
#pragma unroll
                for (int c = 0; c < 8; ++c) o[c] += (float)a[c];
            }
            bf16x8 wv;
#pragma unroll
            for (int c = 0; c < 8; ++c) wv[c] = (bf16)o[c];
            *(bf16x8*)(outH + (size_t)r * D + lc * 8) = wv;
        }
    } else if (KIND == 1 || KIND == 6) {
        if (q == 0) {
            bf16x8 wv;
#pragma unroll
            for (int c = 0; c < 8; ++c) wv[c] = (bf16)(acc[c] * rs);
            *(bf16x8*)(outH + (size_t)r * D + lc * 8) = wv;
        }
        if (KIND == 6 && lane == 0) rowfac[r] = (cnt > 0) ? 1.0f : 0.0f;
    } else if (KIND == 2) {
        if (q == 0) {
            bf16x8 wv;
#pragma unroll
            for (int c = 0; c < 8; ++c) wv[c] = (bf16)fmaxf(acc[c] * rs, 0.0f);
            *(bf16x8*)(outH + (size_t)r * D + lc * 8) = wv;
        } else if (q == 1) {
            float4 o0 = { fmaxf(acc[0] * rs, 0.0f), fmaxf(acc[1] * rs, 0.0f),
                          fmaxf(acc[2] * rs, 0.0f), fmaxf(acc[3] * rs, 0.0f) };
            float4 o1 = { fmaxf(acc[4] * rs, 0.0f), fmaxf(acc[5] * rs, 0.0f),
                          fmaxf(acc[6] * rs, 0.0f), fmaxf(acc[7] * rs, 0.0f) };
            *(float4*)(outF + (size_t)r * D + lc * 8) = o0;
            *(float4*)(outF + (size_t)r * D + lc * 8 + 4) = o1;
        }
    } else {  // KIND 7
        if (q == 0) {
            bf16x8 wv;
#pragma unroll
            for (int c = 0; c < 8; ++c) wv[c] = (bf16)(acc[c] * rs);
            *(bf16x8*)(outH + (size_t)r * D + lc * 8) = wv;
        } else if (q == 1) {
            bf16x8 wv;
#pragma unroll
            for (int c = 0; c < 8; ++c) wv[c] = (bf16)(acc2[c] * rs);
            *(bf16x8*)(outH2 + (size_t)r * D + lc * 8) = wv;
        }
        if (lane == 0) rowfac[r] = sd * rs;
    }
}

extern "C" void kernel_launch(void* const* d_in, const int* in_sizes, int n_in,
                              void* d_out, int out_size, void* d_ws, size_t ws_size,
                              hipStream_t stream) {
    const float* vfeat  = (const float*)d_in[0];
    const float* efeat  = (const float*)d_in[1];
    const float* invDV  = (const float*)d_in[2];
    const float* invDE  = (const float*)d_in[3];
    const int*   inc_v  = (const int*)d_in[4];
    const int*   inc_e  = (const int*)d_in[5];
    const int*   eM_row = (const int*)d_in[6];
    const int*   eM_col = (const int*)d_in[7];
    const float* eM_val = (const float*)d_in[8];
    const int*   vM_row = (const int*)d_in[9];
    const int*   vM_col = (const int*)d_in[10];
    const float* vM_val = (const float*)d_in[11];
    const float* W_psi1 = (const float*)d_in[12];
    const float* b_psi1 = (const float*)d_in[13];
    const float* W_psi2 = (const float*)d_in[14];
    const float* b_psi2 = (const float*)d_in[15];
    const float* W_v    = (const float*)d_in[16];
    const float* W_e    = (const float*)d_in[17];

    const int N = in_sizes[0] / D;
    const int M = in_sizes[1] / D;
    const int E = in_sizes[4];
    const int nnzE = in_sizes[6];
    const int nnzV = in_sizes[9];
    const int TH = 2 * E + nnzE + nnzV;

    float* out = (float*)d_out;
    float* vfeat_new = out;                     // N*D
    float* efeat_new = out + (size_t)N * D;     // M*D

    const int T = 2 * M + 2 * N + 4;

    // bucket geometry (targets ~5-6k items/bucket)
    const int shE = 8, shV = 10, shEr = 9, shVr = 10;
    auto cdiv = [](int a, int b) { return (a + b - 1) / b; };
    const int nbE  = cdiv(M, 1 << shE);
    const int nbV  = cdiv(N, 1 << shV);
    const int nbEr = cdiv(M, 1 << shEr);
    const int nbVr = cdiv(N, 1 << shVr);
    const int NB = nbE + nbV + nbEr + nbVr;   // 315 for the bench sizes (<=1024 required)
    const int4 rbb   = { 0, nbE, nbE + nbV, nbE + nbV + nbEr };
    const int4 SHv   = { shE, shV, shEr, shVr };
    const int4 Kkeys = { M, N, M, N };
    const int bV  = M + 1;
    const int bEr = bV + (N + 1);
    const int bVr = bEr + (M + 1);
    const int4 rbOff = { 0, bV, bEr, bVr };

    // workspace layout (bf16 first, 16B-aligned sections)
    bf16* nA  = (bf16*)d_ws;                    // N*D  vfeatH
    bf16* nB  = nA + (size_t)N * D;             // N*D  vf2preW
    bf16* nC  = nB + (size_t)N * D;             // N*D  vf2W -> vnewH
    bf16* mE  = nC + (size_t)N * D;             // M*D  efeatH
    bf16* mWe = mE + (size_t)M * D;             // M*D  efW_e -> A' (mA)
    bf16* mV  = mWe + (size_t)M * D;            // M*D  efW_v
    bf16* mB  = mV + (size_t)M * D;             // M*D  _efeatV
    bf16* mC  = mB + (size_t)M * D;             // M*D  ef3preW
    bf16* mP  = mC + (size_t)M * D;             // M*D  psi gather out (1 then 2)
    bf16* mA  = mWe;                            // alias: A' after efW_e dead
    float* W1f = (float*)(mP + (size_t)M * D);  // 128*256
    float* W2f = W1f + 128 * 256;               // 128*256
    float* b1f = W2f + 128 * 256;               // 128
    float* b2f = b1f + 128;                     // 128
    float* rowfac = b2f + 128;                  // M
    int* off_all = (int*)(rowfac + M);          // T
    int* cnt_c   = off_all + T;                 // NB   (memset with bcur)
    int* bcur    = cnt_c + NB;                  // NB
    int* coarse_off = bcur + NB;                // NB+1
    int* gs_all  = coarse_off + NB + 1;         // TH (final)
    int* bkT     = gs_all + TH;                 // TH (staging)
    float* wfin  = (float*)(bkT + TH);          // nnzE+nnzV (final)
    float* wTst  = wfin + (nnzE + nnzV);        // nnzE+nnzV (staging)
    float* w_sh  = wfin - (size_t)2 * E;        // final, indexed by slot >= 2E
    float* wT_sh = wTst - (size_t)2 * E;        // staging, indexed by slot >= 2E

    int* offE  = off_all;
    int* offV  = off_all + bV;
    int* offEr = off_all + bEr;
    int* offVr = off_all + bVr;

    const dim3 TB(256);

    // ---- CSR build: coarse hist -> tiny scan -> bucketed append -> per-bucket finalize ----
    hipMemsetAsync(cnt_c, 0, (size_t)(2 * NB) * 4, stream);
    coarse_hist<<<cdiv(TH, BTILE), TB, 0, stream>>>(
        inc_e, inc_v, eM_row, vM_row, E, nnzE, nnzV, rbb, SHv, NB, cnt_c);
    scan_small<<<1, TB, 0, stream>>>(cnt_c, NB, coarse_off);
    bucket_pass<<<cdiv(TH, BTILE), TB, 0, stream>>>(
        inc_e, inc_v, eM_row, eM_col, eM_val, vM_row, vM_col, vM_val,
        E, nnzE, nnzV, rbb, SHv, NB, coarse_off, bcur, bkT, wT_sh);
    finalize_pass<<<NB, TB, 0, stream>>>(
        E, rbOff, rbb, SHv, Kkeys, coarse_off, bkT, wT_sh, off_all, gs_all, w_sh);

    // ---- bf16 inputs + folded weights ----
    cvt_bf16<<<cdiv(N * D / 4, 256), TB, 0, stream>>>(vfeat, nA, N * D / 4);
    cvt_bf16<<<cdiv(M * D / 4, 256), TB, 0, stream>>>(efeat, mE, M * D / 4);
    wfold<<<257, TB, 0, stream>>>(W_v, W_psi1, b_psi1, W_e, W_psi2, b_psi2,
                                  W1f, b1f, W2f, b2f);

    // ---- pipeline (fully in Wv/We-transformed space for the two chains) ----
    // efW_e = efeat @ W_e^T ; efW_v = efeat @ W_v^T
    gemm_mfma<<<cdiv(M, 128), TB, 0, stream>>>(mE, W_e, D, mWe, M);
    gemm_mfma<<<cdiv(M, 128), TB, 0, stream>>>(mE, W_v, D, mV, M);
    // vf2preW = mean_v(efW_e[inc_e] * invDE[inc_e]) -> nB
    seg_gather<1><<<cdiv(N, 4), TB, 0, stream>>>(
        mWe, nullptr, offV, gs_all, nullptr, invDE, nullptr, nB, nullptr, nullptr, nullptr, N);
    // vf2W = spmm_V(vf2preW) -> nC
    seg_gather<0><<<cdiv(N, 4), TB, 0, stream>>>(
        nB, nullptr, offVr, gs_all, w_sh, nullptr, nullptr, nC, nullptr, nullptr, nullptr, N);
    // FUSED psi1: mP = mean_w(vfeatH*dv); mC = ef3preW = mean(vf2W); rowfac = sd/cnt
    seg_gather<7><<<cdiv(M, 4), TB, 0, stream>>>(
        nA, nC, offE, gs_all, nullptr, invDV, nullptr, mP, mC, nullptr, rowfac, M);
    // A' = [mP ; mE*fac] @ W1f^T + fac*b1f -> mA (bf16)
    gemm_psi<<<cdiv(M, 128), TB, 0, stream>>>(
        mP, mE, rowfac, W1f, b1f, nullptr, nullptr, mA, M, 0);
    // _efeatV = spmm_E(A') + efW_v -> mB
    seg_gather<0><<<cdiv(M, 4), TB, 0, stream>>>(
        mA, nullptr, offEr, gs_all, w_sh, nullptr, mV, mB, nullptr, nullptr, nullptr, M);
    // vfeat_new = relu(mean_v(_efeatV)) -> d_out fp32 + nC bf16 (vf2W dead)
    seg_gather<2><<<cdiv(N, 4), TB, 0, stream>>>(
        mB, nullptr, offV, gs_all, nullptr, nullptr, nullptr, nC, nullptr, vfeat_new, nullptr, N);
    // psi2: mP = mean(vnewH); rowfac = [cnt>0]
    seg_gather<6><<<cdiv(M, 4), TB, 0, stream>>>(
        nC, nullptr, offE, gs_all, nullptr, nullptr, nullptr, mP, nullptr, nullptr, rowfac, M);
    // efeat_new = relu([mP ; mE*fac] @ W2f^T + fac*b2f + ef3preW) -> d_out
    gemm_psi<<<cdiv(M, 128), TB, 0, stream>>>(
        mP, mE, rowfac, W2f, b2f, mC, efeat_new, nullptr, M, 1);
}